// Round 4
// baseline (632.852 us; speedup 1.0000x reference)
//
#include <hip/hip_runtime.h>
#include <math.h>

#define SS 2048
#define DD 1024
#define HH 16

typedef _Float16 f16;
typedef _Float16 half8 __attribute__((ext_vector_type(8)));
typedef float f32x4 __attribute__((ext_vector_type(4)));

#define LOG2E 1.44269504f
#define MASKNEG -30000.0f

__device__ __forceinline__ void gload16(const void* g, void* lds) {
    __builtin_amdgcn_global_load_lds(
        (const __attribute__((address_space(1))) unsigned int*)g,
        (__attribute__((address_space(3))) unsigned int*)lds, 16, 0, 0);
}

// DPP 16-lane reductions (VALU pipe, no LDS/ds_swizzle traffic).
// xor1 = quad_perm[1,0,3,2]=0xB1, xor2 = quad_perm[2,3,0,1]=0x4E,
// then row_ror:4 (0x124) and row_ror:8 (0x128) complete the 16-lane window.
__device__ __forceinline__ float dpp_max16(float x) {
    float y;
    y = __uint_as_float(__builtin_amdgcn_mov_dpp(__float_as_uint(x), 0xB1, 0xF, 0xF, false));
    x = fmaxf(x, y);
    y = __uint_as_float(__builtin_amdgcn_mov_dpp(__float_as_uint(x), 0x4E, 0xF, 0xF, false));
    x = fmaxf(x, y);
    y = __uint_as_float(__builtin_amdgcn_mov_dpp(__float_as_uint(x), 0x124, 0xF, 0xF, false));
    x = fmaxf(x, y);
    y = __uint_as_float(__builtin_amdgcn_mov_dpp(__float_as_uint(x), 0x128, 0xF, 0xF, false));
    x = fmaxf(x, y);
    return x;
}
__device__ __forceinline__ float dpp_sum16(float x) {
    float y;
    y = __uint_as_float(__builtin_amdgcn_mov_dpp(__float_as_uint(x), 0xB1, 0xF, 0xF, false));
    x += y;
    y = __uint_as_float(__builtin_amdgcn_mov_dpp(__float_as_uint(x), 0x4E, 0xF, 0xF, false));
    x += y;
    y = __uint_as_float(__builtin_amdgcn_mov_dpp(__float_as_uint(x), 0x124, 0xF, 0xF, false));
    x += y;
    y = __uint_as_float(__builtin_amdgcn_mov_dpp(__float_as_uint(x), 0x128, 0xF, 0xF, false));
    x += y;
    return x;
}

// ============================================================
// prep 1: f32 -> f16 elementwise for query/key/value
// ============================================================
__global__ __launch_bounds__(256)
void cvt_x(const float* __restrict__ q, const float* __restrict__ k,
           const float* __restrict__ v, f16* __restrict__ oq,
           f16* __restrict__ ok, f16* __restrict__ ov)
{
    const int z = blockIdx.z;
    const float* src = z == 0 ? q : z == 1 ? k : v;
    f16* dst = z == 0 ? oq : z == 1 ? ok : ov;
    size_t i = ((size_t)blockIdx.x * 256 + threadIdx.x) * 8;
    float4 v0 = *reinterpret_cast<const float4*>(src + i);
    float4 v1 = *reinterpret_cast<const float4*>(src + i + 4);
    half8 h;
    h[0] = (f16)v0.x; h[1] = (f16)v0.y; h[2] = (f16)v0.z; h[3] = (f16)v0.w;
    h[4] = (f16)v1.x; h[5] = (f16)v1.y; h[6] = (f16)v1.z; h[7] = (f16)v1.w;
    *reinterpret_cast<half8*>(dst + i) = h;
}

// ============================================================
// prep 2: W (k,n) f32 -> WT (n,k) f16, 64x64 tiles through LDS
// ============================================================
__global__ __launch_bounds__(256)
void cvt_wT(const float* __restrict__ wq, const float* __restrict__ wk,
            const float* __restrict__ wv, const float* __restrict__ wo,
            f16* __restrict__ oq, f16* __restrict__ ok,
            f16* __restrict__ ov, f16* __restrict__ oo)
{
    __shared__ float Lt[64][65];
    const int z = blockIdx.z;
    const float* W = z == 0 ? wq : z == 1 ? wk : z == 2 ? wv : wo;
    f16* WT = z == 0 ? oq : z == 1 ? ok : z == 2 ? ov : oo;
    const int n0 = blockIdx.x * 64, k0 = blockIdx.y * 64;
    const int t = threadIdx.x;
    {
        int row = t >> 2;               // k-local
        int c0  = (t & 3) * 16;         // n-local
#pragma unroll
        for (int u = 0; u < 4; ++u) {
            float4 x = *reinterpret_cast<const float4*>(
                &W[(size_t)(k0 + row) * DD + n0 + c0 + u * 4]);
            Lt[row][c0 + u * 4 + 0] = x.x;
            Lt[row][c0 + u * 4 + 1] = x.y;
            Lt[row][c0 + u * 4 + 2] = x.z;
            Lt[row][c0 + u * 4 + 3] = x.w;
        }
    }
    __syncthreads();
    {
        int n  = t >> 2;                // n-local
        int kc = (t & 3) * 16;          // k-local chunk
        half8 h0, h1;
#pragma unroll
        for (int u = 0; u < 8; ++u) h0[u] = (f16)Lt[kc + u][n];
#pragma unroll
        for (int u = 0; u < 8; ++u) h1[u] = (f16)Lt[kc + 8 + u][n];
        f16* dst = &WT[(size_t)(n0 + n) * DD + k0 + kc];
        *reinterpret_cast<half8*>(dst) = h0;
        *reinterpret_cast<half8*>(dst + 8) = h1;
    }
}

// ============================================================
// prep 3: fused bias+mask: bmT[b][h][i][j] f16 =
//   mask[b,i,j] ? rpb[j,i,h]*log2e : -30000
// Reads rpb coalesced along (i,h); mask coalesced along j.
// grid (SS/64 i-tiles, SS/64 j-tiles), 256 threads.
// ============================================================
__global__ __launch_bounds__(256)
void cvt_bm(const float* __restrict__ rpb, const int* __restrict__ mask,
            f16* __restrict__ bmT)
{
    const int t  = threadIdx.x;
    const int i0 = blockIdx.x * 64;
    const int j0 = blockIdx.y * 64;
    const int il = t >> 2;              // 0..63 (i-local)
    const int h0 = (t & 3) * 4;         // 0,4,8,12
    const int i  = i0 + il;
    const float* src = rpb + ((size_t)j0 * SS + i) * HH + h0;
    const int* m0p = mask + (size_t)i * SS + j0;
    const int* m1p = m0p + (size_t)SS * SS;
    f16* d0 = bmT + ((size_t)(0 * HH + h0) * SS + i) * SS + j0;
    f16* d1 = bmT + ((size_t)(1 * HH + h0) * SS + i) * SS + j0;
    for (int jc = 0; jc < 8; ++jc) {
        half8 hb[4];
#pragma unroll
        for (int jj = 0; jj < 8; ++jj) {
            float4 v = *reinterpret_cast<const float4*>(
                src + (size_t)(jc * 8 + jj) * (SS * HH));
            hb[0][jj] = (f16)(v.x * LOG2E);
            hb[1][jj] = (f16)(v.y * LOG2E);
            hb[2][jj] = (f16)(v.z * LOG2E);
            hb[3][jj] = (f16)(v.w * LOG2E);
        }
        int4 ma = *reinterpret_cast<const int4*>(m0p + jc * 8);
        int4 mb = *reinterpret_cast<const int4*>(m0p + jc * 8 + 4);
        int4 mc = *reinterpret_cast<const int4*>(m1p + jc * 8);
        int4 md = *reinterpret_cast<const int4*>(m1p + jc * 8 + 4);
        int mv0[8] = {ma.x, ma.y, ma.z, ma.w, mb.x, mb.y, mb.z, mb.w};
        int mv1[8] = {mc.x, mc.y, mc.z, mc.w, md.x, md.y, md.z, md.w};
#pragma unroll
        for (int k = 0; k < 4; ++k) {
            half8 w0, w1;
#pragma unroll
            for (int jj = 0; jj < 8; ++jj) {
                w0[jj] = mv0[jj] ? hb[k][jj] : (f16)MASKNEG;
                w1[jj] = mv1[jj] ? hb[k][jj] : (f16)MASKNEG;
            }
            *reinterpret_cast<half8*>(d0 + (size_t)k * SS * SS + jc * 8) = w0;
            *reinterpret_cast<half8*>(d1 + (size_t)k * SS * SS + jc * 8) = w1;
        }
    }
}

// ============================================================
// Fused Q/K/V projection GEMM, f16 MFMA 16x16x32, 128x128 tile BK=64.
//   gz=0: Q = (query@Wq + bq)*0.125*log2e -> f16 [bh][s][64]
//   gz=1: K                               -> f16 [bh][s][64]
//   gz=2: V^T = (value@Wv + bv)^T         -> f16 [bh][d][s]
// ============================================================
__global__ __launch_bounds__(256)
void proj3(const f16* __restrict__ Xq, const f16* __restrict__ Xk,
           const f16* __restrict__ Xv, const f16* __restrict__ WqT,
           const f16* __restrict__ WkT, const f16* __restrict__ WvT,
           const float* __restrict__ bq, const float* __restrict__ bk,
           const float* __restrict__ bv,
           f16* __restrict__ Qo, f16* __restrict__ Ko, f16* __restrict__ VTo)
{
    __shared__ f16 As[128 * 64];
    __shared__ f16 Bs[128 * 64];
    const int t = threadIdx.x, wid = t >> 6, l = t & 63, c = l & 15, g = l >> 4;
    const int gz = blockIdx.z;
    const f16 *Ap, *Bp; const float* bias; int m0, n0;
    if (gz == 2) { Ap = WvT; Bp = Xv; bias = bv; m0 = blockIdx.x * 128; n0 = blockIdx.y * 128; }
    else if (gz == 1) { Ap = Xk; Bp = WkT; bias = bk; m0 = blockIdx.y * 128; n0 = blockIdx.x * 128; }
    else { Ap = Xq; Bp = WqT; bias = bq; m0 = blockIdx.y * 128; n0 = blockIdx.x * 128; }
    const int wm = wid >> 1, wn = wid & 1;
    f32x4 acc[4][4] = {};
    char* AsB = (char*)As; char* BsB = (char*)Bs;

    for (int k0 = 0; k0 < DD; k0 += 64) {
        __syncthreads();
#pragma unroll
        for (int j = 0; j < 4; ++j) {
            int row = wid * 32 + j * 8 + (l >> 3);
            int slot = (l & 7) ^ (row & 7);
            gload16(Ap + (size_t)(m0 + row) * DD + k0 + slot * 8,
                    AsB + (wid * 32 + j * 8) * 128);
            gload16(Bp + (size_t)(n0 + row) * DD + k0 + slot * 8,
                    BsB + (wid * 32 + j * 8) * 128);
        }
        __syncthreads();
#pragma unroll
        for (int ks = 0; ks < 2; ++ks) {
            half8 af[4];
#pragma unroll
            for (int mt = 0; mt < 4; ++mt) {
                int row = wm * 64 + mt * 16 + c;
                af[mt] = *(const half8*)(AsB + row * 128 +
                         ((ks * 64 + g * 16) ^ ((row & 7) << 4)));
            }
#pragma unroll
            for (int nt = 0; nt < 4; ++nt) {
                int row = wn * 64 + nt * 16 + c;
                half8 bf = *(const half8*)(BsB + row * 128 +
                           ((ks * 64 + g * 16) ^ ((row & 7) << 4)));
#pragma unroll
                for (int mt = 0; mt < 4; ++mt)
                    acc[mt][nt] = __builtin_amdgcn_mfma_f32_16x16x32_f16(
                        af[mt], bf, acc[mt][nt], 0, 0, 0);
            }
        }
    }

    const float post = (gz == 0) ? 0.125f * LOG2E : 1.0f;
    if (gz < 2) {
        f16* dst = gz ? Ko : Qo;
#pragma unroll
        for (int nt = 0; nt < 4; ++nt) {
            int n = n0 + wn * 64 + nt * 16 + c;
            float bn = bias[n];
            int h = n >> 6, hd = n & 63;
#pragma unroll
            for (int mt = 0; mt < 4; ++mt)
#pragma unroll
                for (int reg = 0; reg < 4; ++reg) {
                    int m = m0 + wm * 64 + mt * 16 + 4 * g + reg;
                    int b = m >> 11, s = m & (SS - 1);
                    dst[(((size_t)(b * HH + h)) * SS + s) * 64 + hd] =
                        (f16)((acc[mt][nt][reg] + bn) * post);
                }
        }
    } else {
#pragma unroll
        for (int mt = 0; mt < 4; ++mt)
#pragma unroll
            for (int reg = 0; reg < 4; ++reg) {
                int m = m0 + wm * 64 + mt * 16 + 4 * g + reg;   // d index
                float bd = bias[m];
                int h = m >> 6, dl = m & 63;
#pragma unroll
                for (int nt = 0; nt < 4; ++nt) {
                    int n = n0 + wn * 64 + nt * 16 + c;          // s index
                    int b = n >> 11, s = n & (SS - 1);
                    VTo[(((size_t)(b * HH + h)) * 64 + dl) * SS + s] =
                        (f16)(acc[mt][nt][reg] + bd);
                }
            }
    }
}

// ============================================================
// Flash attention, f16 MFMA, base-2 softmax. Block = 64 q-rows of one
// (b,h); 4 waves x 16 rows. K-tiles 64. bm (bias+mask) pre-fused f16.
// LDS: Qs 8K (shared with f16 P after Q is register-cached), Ks 8K,
// Vs 8K = 24 KB -> 5-6 blocks/CU. DPP softmax (no ds_swizzle), sum
// reduction deferred to epilogue.
// ============================================================
__global__ __launch_bounds__(256, 5)
void attn_fwd(const f16* __restrict__ Qw, const f16* __restrict__ Kw,
              const f16* __restrict__ VTw, const f16* __restrict__ bmT,
              f16* __restrict__ AOh)
{
    __shared__ f16 Qs[64 * 64];   // Q staging, then P (f16)
    __shared__ f16 Ks[64 * 64];
    __shared__ f16 Vs[64 * 64];
    char* QsB = (char*)Qs; char* KsB = (char*)Ks; char* VsB = (char*)Vs;

    const int t = threadIdx.x, wid = t >> 6, l = t & 63, c = l & 15, g = l >> 4;
    const int bh = blockIdx.x, b = bh >> 4, h = bh & 15;
    const int q0 = blockIdx.y * 64;
    const size_t baseSD = (size_t)bh * SS * 64;      // Q/K rows base
    const size_t baseDS = (size_t)bh * 64 * SS;      // V^T rows base
    const f16* bmB = bmT + (size_t)bh * SS * SS;     // [i][j] for this (b,h)

    // per-reg bm row pointers (q-row fixed per reg; advances by j0 + c)
    const f16* bmRow[4];
#pragma unroll
    for (int reg = 0; reg < 4; ++reg)
        bmRow[reg] = bmB + (size_t)(q0 + wid * 16 + 4 * g + reg) * SS + c;

    // stage Q (64 rows x 64 f16), pre-swizzled source -> linear LDS
#pragma unroll
    for (int j = 0; j < 2; ++j) {
        int row = wid * 16 + j * 8 + (l >> 3);
        int slot = (l & 7) ^ (row & 7);
        gload16(Qw + baseSD + (size_t)(q0 + row) * 64 + slot * 8,
                QsB + (wid * 16 + j * 8) * 128);
    }

    half8 qf[2];
    f32x4 acc_o[4] = {};
    float mrow[4], lp[4];
#pragma unroll
    for (int r = 0; r < 4; ++r) { mrow[r] = -INFINITY; lp[r] = 0.f; }

    for (int kt = 0; kt < SS / 64; ++kt) {
        const int j0 = kt * 64;
        __syncthreads();   // A: prev PV done (kt=0: nothing)
        // stage K [key][hd] and V^T [d][key]
#pragma unroll
        for (int j = 0; j < 2; ++j) {
            int row = wid * 16 + j * 8 + (l >> 3);
            int slot = (l & 7) ^ (row & 7);
            gload16(Kw + baseSD + (size_t)(j0 + row) * 64 + slot * 8,
                    KsB + (wid * 16 + j * 8) * 128);
            gload16(VTw + baseDS + (size_t)row * SS + j0 + slot * 8,
                    VsB + (wid * 16 + j * 8) * 128);
        }
        __syncthreads();   // B: K/V staged (Q staged at kt=0 too)
        // issue bm loads now; consumed after the QK MFMAs (latency hidden)
        f16 bm[4][4];
#pragma unroll
        for (int reg = 0; reg < 4; ++reg) {
            const f16* p = bmRow[reg] + j0;
#pragma unroll
            for (int nt = 0; nt < 4; ++nt) bm[reg][nt] = p[nt * 16];
        }
        if (kt == 0) {
#pragma unroll
            for (int ks = 0; ks < 2; ++ks) {
                int row = wid * 16 + c;
                qf[ks] = *(const half8*)(QsB + row * 128 +
                         ((ks * 64 + g * 16) ^ ((row & 7) << 4)));
            }
        }
        // QK^T (log2-domain scores; Q pre-scaled by 0.125*log2e)
        f32x4 sc[4] = {};
#pragma unroll
        for (int ks = 0; ks < 2; ++ks)
#pragma unroll
            for (int nt = 0; nt < 4; ++nt) {
                int row = nt * 16 + c;
                half8 kf = *(const half8*)(KsB + row * 128 +
                           ((ks * 64 + g * 16) ^ ((row & 7) << 4)));
                sc[nt] = __builtin_amdgcn_mfma_f32_16x16x32_f16(
                    qf[ks], kf, sc[nt], 0, 0, 0);
            }
        // bias/mask + online softmax (base 2), DPP row-max, deferred sum
#pragma unroll
        for (int reg = 0; reg < 4; ++reg) {
            float s0 = sc[0][reg] + (float)bm[reg][0];
            float s1 = sc[1][reg] + (float)bm[reg][1];
            float s2 = sc[2][reg] + (float)bm[reg][2];
            float s3 = sc[3][reg] + (float)bm[reg][3];
            float rm = fmaxf(fmaxf(s0, s1), fmaxf(s2, s3));
            rm = dpp_max16(rm);
            float mn = fmaxf(mrow[reg], rm);
            float scal = exp2f(mrow[reg] - mn);   // exp2(-inf)=0 first tile
            mrow[reg] = mn;
            float p0 = exp2f(s0 - mn), p1 = exp2f(s1 - mn);
            float p2 = exp2f(s2 - mn), p3 = exp2f(s3 - mn);
            sc[0][reg] = p0; sc[1][reg] = p1;
            sc[2][reg] = p2; sc[3][reg] = p3;
            lp[reg] = lp[reg] * scal + (p0 + p1 + p2 + p3);
#pragma unroll
            for (int nt = 0; nt < 4; ++nt) acc_o[nt][reg] *= scal;
        }
        // write P as f16 into Qs region (swizzled); each wave touches only
        // its own 16-row band, so sharing with Q staging is race-free.
#pragma unroll
        for (int reg = 0; reg < 4; ++reg) {
            int qrl = wid * 16 + 4 * g + reg;
            char* pr = QsB + qrl * 128;
            int sw = (qrl & 7) << 4;
#pragma unroll
            for (int nt = 0; nt < 4; ++nt)
                *(f16*)(pr + ((nt * 32 + c * 2) ^ sw)) = (f16)sc[nt][reg];
        }
        __syncthreads();   // C: P ready
        // PV: acc_o += P @ V
#pragma unroll
        for (int ks = 0; ks < 2; ++ks) {
            int prow = wid * 16 + c;
            half8 pa = *(const half8*)(QsB + prow * 128 +
                       ((ks * 64 + g * 16) ^ ((prow & 7) << 4)));
#pragma unroll
            for (int nt = 0; nt < 4; ++nt) {
                int row = nt * 16 + c;
                half8 vf = *(const half8*)(VsB + row * 128 +
                           ((ks * 64 + g * 16) ^ ((row & 7) << 4)));
                acc_o[nt] = __builtin_amdgcn_mfma_f32_16x16x32_f16(
                    pa, vf, acc_o[nt], 0, 0, 0);
            }
        }
    }
    // epilogue: reduce deferred sums, normalize, store f16 AO
#pragma unroll
    for (int reg = 0; reg < 4; ++reg) {
        float lrow = dpp_sum16(lp[reg]);
        float inv = 1.0f / lrow;
        int qrow = q0 + wid * 16 + 4 * g + reg;
#pragma unroll
        for (int nt = 0; nt < 4; ++nt)
            AOh[((size_t)b * SS + qrow) * DD + h * 64 + nt * 16 + c] =
                (f16)(acc_o[nt][reg] * inv);
    }
}

// ============================================================
// Output projection: out(f32) = AO(f16) @ Wo + bo.
// ============================================================
__global__ __launch_bounds__(256)
void gemm_out(const f16* __restrict__ A, const f16* __restrict__ BT,
              const float* __restrict__ bias, float* __restrict__ out)
{
    __shared__ f16 As[128 * 64];
    __shared__ f16 Bs[128 * 64];
    const int t = threadIdx.x, wid = t >> 6, l = t & 63, c = l & 15, g = l >> 4;
    const int m0 = blockIdx.y * 128, n0 = blockIdx.x * 128;
    const int wm = wid >> 1, wn = wid & 1;
    f32x4 acc[4][4] = {};
    char* AsB = (char*)As; char* BsB = (char*)Bs;

    for (int k0 = 0; k0 < DD; k0 += 64) {
        __syncthreads();
#pragma unroll
        for (int j = 0; j < 4; ++j) {
            int row = wid * 32 + j * 8 + (l >> 3);
            int slot = (l & 7) ^ (row & 7);
            gload16(A + (size_t)(m0 + row) * DD + k0 + slot * 8,
                    AsB + (wid * 32 + j * 8) * 128);
            gload16(BT + (size_t)(n0 + row) * DD + k0 + slot * 8,
                    BsB + (wid * 32 + j * 8) * 128);
        }
        __syncthreads();
#pragma unroll
        for (int ks = 0; ks < 2; ++ks) {
            half8 af[4];
#pragma unroll
            for (int mt = 0; mt < 4; ++mt) {
                int row = wm * 64 + mt * 16 + c;
                af[mt] = *(const half8*)(AsB + row * 128 +
                         ((ks * 64 + g * 16) ^ ((row & 7) << 4)));
            }
#pragma unroll
            for (int nt = 0; nt < 4; ++nt) {
                int row = wn * 64 + nt * 16 + c;
                half8 bf = *(const half8*)(BsB + row * 128 +
                           ((ks * 64 + g * 16) ^ ((row & 7) << 4)));
#pragma unroll
                for (int mt = 0; mt < 4; ++mt)
                    acc[mt][nt] = __builtin_amdgcn_mfma_f32_16x16x32_f16(
                        af[mt], bf, acc[mt][nt], 0, 0, 0);
            }
        }
    }
#pragma unroll
    for (int nt = 0; nt < 4; ++nt) {
        int n = n0 + wn * 64 + nt * 16 + c;
        float bn = bias[n];
#pragma unroll
        for (int mt = 0; mt < 4; ++mt)
#pragma unroll
            for (int reg = 0; reg < 4; ++reg) {
                int m = m0 + wm * 64 + mt * 16 + 4 * g + reg;
                out[(size_t)m * DD + n] = acc[mt][nt][reg] + bn;
            }
    }
}

extern "C" void kernel_launch(void* const* d_in, const int* in_sizes, int n_in,
                              void* d_out, int out_size, void* d_ws, size_t ws_size,
                              hipStream_t stream)
{
    (void)in_sizes; (void)n_in; (void)out_size; (void)ws_size;

    const float* query = (const float*)d_in[0];
    const float* key   = (const float*)d_in[1];
    const float* value = (const float*)d_in[2];
    const int*   mask  = (const int*)d_in[3];
    const float* rpb   = (const float*)d_in[4];
    const float* Wq = (const float*)d_in[5];  const float* bq = (const float*)d_in[6];
    const float* Wk = (const float*)d_in[7];  const float* bk = (const float*)d_in[8];
    const float* Wv = (const float*)d_in[9];  const float* bv = (const float*)d_in[10];
    const float* Wo = (const float*)d_in[11]; const float* bo = (const float*)d_in[12];
    float* out = (float*)d_out;

    // workspace layout (f16 elements). AOh aliases Xq (dead after proj3).
    const size_t NX = (size_t)2 * SS * DD;   // 4096x1024
    const size_t NW = (size_t)DD * DD;       // 1024x1024
    f16* Xq   = (f16*)d_ws;
    f16* Xk   = Xq + NX;
    f16* Xv   = Xk + NX;
    f16* WqT  = Xv + NX;
    f16* WkT  = WqT + NW;
    f16* WvT  = WkT + NW;
    f16* WoT  = WvT + NW;
    f16* Qw   = WoT + NW;
    f16* Kw   = Qw + NX;
    f16* VTw  = Kw + NX;
    f16* bmT  = VTw + NX;                    // 2*16*2048*2048 f16 = 256 MB
    f16* AOh  = Xq;   // alias

    cvt_x<<<dim3(NX / 2048, 1, 3), 256, 0, stream>>>(query, key, value, Xq, Xk, Xv);
    cvt_wT<<<dim3(16, 16, 4), 256, 0, stream>>>(Wq, Wk, Wv, Wo, WqT, WkT, WvT, WoT);
    cvt_bm<<<dim3(SS / 64, SS / 64), 256, 0, stream>>>(rpb, mask, bmT);
    proj3<<<dim3(8, 32, 3), 256, 0, stream>>>(Xq, Xk, Xv, WqT, WkT, WvT,
                                              bq, bk, bv, Qw, Kw, VTw);
    attn_fwd<<<dim3(2 * HH, SS / 64), 256, 0, stream>>>(Qw, Kw, VTw, bmT, AOh);
    gemm_out<<<dim3(8, 32), 256, 0, stream>>>(AOh, WoT, bo, out);
}

// Round 5
// 441.924 us; speedup vs baseline: 1.4320x; 1.4320x over previous
//
#include <hip/hip_runtime.h>
#include <math.h>

#define SS 2048
#define DD 1024
#define HH 16

typedef _Float16 f16;
typedef _Float16 half8 __attribute__((ext_vector_type(8)));
typedef float f32x4 __attribute__((ext_vector_type(4)));
typedef unsigned long long u64;

#define LOG2E 1.44269504f
#define MASKNEG -30000.0f

__device__ __forceinline__ void gload16(const void* g, void* lds) {
    __builtin_amdgcn_global_load_lds(
        (const __attribute__((address_space(1))) unsigned int*)g,
        (__attribute__((address_space(3))) unsigned int*)lds, 16, 0, 0);
}

// DPP 16-lane reductions (VALU pipe, no LDS traffic).
__device__ __forceinline__ float dpp_max16(float x) {
    float y;
    y = __uint_as_float(__builtin_amdgcn_mov_dpp(__float_as_uint(x), 0xB1, 0xF, 0xF, false));
    x = fmaxf(x, y);
    y = __uint_as_float(__builtin_amdgcn_mov_dpp(__float_as_uint(x), 0x4E, 0xF, 0xF, false));
    x = fmaxf(x, y);
    y = __uint_as_float(__builtin_amdgcn_mov_dpp(__float_as_uint(x), 0x124, 0xF, 0xF, false));
    x = fmaxf(x, y);
    y = __uint_as_float(__builtin_amdgcn_mov_dpp(__float_as_uint(x), 0x128, 0xF, 0xF, false));
    x = fmaxf(x, y);
    return x;
}
__device__ __forceinline__ float dpp_sum16(float x) {
    float y;
    y = __uint_as_float(__builtin_amdgcn_mov_dpp(__float_as_uint(x), 0xB1, 0xF, 0xF, false));
    x += y;
    y = __uint_as_float(__builtin_amdgcn_mov_dpp(__float_as_uint(x), 0x4E, 0xF, 0xF, false));
    x += y;
    y = __uint_as_float(__builtin_amdgcn_mov_dpp(__float_as_uint(x), 0x124, 0xF, 0xF, false));
    x += y;
    y = __uint_as_float(__builtin_amdgcn_mov_dpp(__float_as_uint(x), 0x128, 0xF, 0xF, false));
    x += y;
    return x;
}

// ============================================================
// prep 1: f32 -> f16 elementwise for query/key/value
// ============================================================
__global__ __launch_bounds__(256)
void cvt_x(const float* __restrict__ q, const float* __restrict__ k,
           const float* __restrict__ v, f16* __restrict__ oq,
           f16* __restrict__ ok, f16* __restrict__ ov)
{
    const int z = blockIdx.z;
    const float* src = z == 0 ? q : z == 1 ? k : v;
    f16* dst = z == 0 ? oq : z == 1 ? ok : ov;
    size_t i = ((size_t)blockIdx.x * 256 + threadIdx.x) * 8;
    float4 v0 = *reinterpret_cast<const float4*>(src + i);
    float4 v1 = *reinterpret_cast<const float4*>(src + i + 4);
    half8 h;
    h[0] = (f16)v0.x; h[1] = (f16)v0.y; h[2] = (f16)v0.z; h[3] = (f16)v0.w;
    h[4] = (f16)v1.x; h[5] = (f16)v1.y; h[6] = (f16)v1.z; h[7] = (f16)v1.w;
    *reinterpret_cast<half8*>(dst + i) = h;
}

// ============================================================
// prep 2: W (k,n) f32 -> WT (n,k) f16, 64x64 tiles through LDS
// ============================================================
__global__ __launch_bounds__(256)
void cvt_wT(const float* __restrict__ wq, const float* __restrict__ wk,
            const float* __restrict__ wv, const float* __restrict__ wo,
            f16* __restrict__ oq, f16* __restrict__ ok,
            f16* __restrict__ ov, f16* __restrict__ oo)
{
    __shared__ float Lt[64][65];
    const int z = blockIdx.z;
    const float* W = z == 0 ? wq : z == 1 ? wk : z == 2 ? wv : wo;
    f16* WT = z == 0 ? oq : z == 1 ? ok : z == 2 ? ov : oo;
    const int n0 = blockIdx.x * 64, k0 = blockIdx.y * 64;
    const int t = threadIdx.x;
    {
        int row = t >> 2;               // k-local
        int c0  = (t & 3) * 16;         // n-local
#pragma unroll
        for (int u = 0; u < 4; ++u) {
            float4 x = *reinterpret_cast<const float4*>(
                &W[(size_t)(k0 + row) * DD + n0 + c0 + u * 4]);
            Lt[row][c0 + u * 4 + 0] = x.x;
            Lt[row][c0 + u * 4 + 1] = x.y;
            Lt[row][c0 + u * 4 + 2] = x.z;
            Lt[row][c0 + u * 4 + 3] = x.w;
        }
    }
    __syncthreads();
    {
        int n  = t >> 2;                // n-local
        int kc = (t & 3) * 16;          // k-local chunk
        half8 h0, h1;
#pragma unroll
        for (int u = 0; u < 8; ++u) h0[u] = (f16)Lt[kc + u][n];
#pragma unroll
        for (int u = 0; u < 8; ++u) h1[u] = (f16)Lt[kc + 8 + u][n];
        f16* dst = &WT[(size_t)(n0 + n) * DD + k0 + kc];
        *reinterpret_cast<half8*>(dst) = h0;
        *reinterpret_cast<half8*>(dst + 8) = h1;
    }
}

// ============================================================
// prep 3: rpb[j][i][h] f32 -> rpbT[h][i][j] f16 (scaled log2e).
// LDS-tiled transpose: block = 16 i x 64 j x all 16 h.
// Reads: 1 KB contiguous per wave (lane-exact). Writes: 128-B full
// lines (8 lanes x 16 B per (h,i) row). Both sides BW-optimal.
// ============================================================
__global__ __launch_bounds__(256)
void cvt_rpbT(const float* __restrict__ rpb, f16* __restrict__ rpbT)
{
    __shared__ f16 Lt[16][16][66];   // [h][i][j], +2 pad
    const int t = threadIdx.x, wid = t >> 6, l = t & 63;
    const int i0 = blockIdx.x * 16;
    const int j0 = blockIdx.y * 64;
    const int il = l >> 2;
    const int h0 = (l & 3) * 4;
#pragma unroll
    for (int p = 0; p < 16; ++p) {
        int jl = p * 4 + wid;
        float4 v = *reinterpret_cast<const float4*>(
            rpb + ((size_t)(j0 + jl) * SS + i0 + il) * HH + h0);
        Lt[h0 + 0][il][jl] = (f16)(v.x * LOG2E);
        Lt[h0 + 1][il][jl] = (f16)(v.y * LOG2E);
        Lt[h0 + 2][il][jl] = (f16)(v.z * LOG2E);
        Lt[h0 + 3][il][jl] = (f16)(v.w * LOG2E);
    }
    __syncthreads();
    const int part = t & 7;
#pragma unroll
    for (int p = 0; p < 8; ++p) {
        int rowid = p * 32 + (t >> 3);
        int h = rowid >> 4, i2 = rowid & 15;
        half8 v = *reinterpret_cast<const half8*>(&Lt[h][i2][part * 8]);
        *reinterpret_cast<half8*>(
            rpbT + ((size_t)h * SS + i0 + i2) * SS + j0 + part * 8) = v;
    }
}

// ============================================================
// prep 4: mask int32 -> bitmask u64[b*SS+i][j/64] via wave ballot.
// 33 MB -> 1 MB (L2-resident in attn).
// ============================================================
__global__ __launch_bounds__(256)
void cvt_maskbits(const int* __restrict__ mask, u64* __restrict__ mb)
{
    const int t = threadIdx.x, wid = t >> 6, l = t & 63;
    const int row = blockIdx.x * 4 + wid;     // b*SS+i
    const int* src = mask + (size_t)row * SS;
    u64* dst = mb + (size_t)row * 32;
    for (int it = 0; it < 32; ++it) {
        int mv = src[it * 64 + l];
        u64 bal = __ballot(mv != 0);
        if (l == 0) dst[it] = bal;
    }
}

// ============================================================
// Fused Q/K/V projection GEMM, f16 MFMA 16x16x32, 128x128 tile BK=64.
//   gz=0: Q = (query@Wq + bq)*0.125*log2e -> f16 [bh][s][64]
//   gz=1: K                               -> f16 [bh][s][64]
//   gz=2: V^T = (value@Wv + bv)^T         -> f16 [bh][d][s]
// ============================================================
__global__ __launch_bounds__(256)
void proj3(const f16* __restrict__ Xq, const f16* __restrict__ Xk,
           const f16* __restrict__ Xv, const f16* __restrict__ WqT,
           const f16* __restrict__ WkT, const f16* __restrict__ WvT,
           const float* __restrict__ bq, const float* __restrict__ bk,
           const float* __restrict__ bv,
           f16* __restrict__ Qo, f16* __restrict__ Ko, f16* __restrict__ VTo)
{
    __shared__ f16 As[128 * 64];
    __shared__ f16 Bs[128 * 64];
    const int t = threadIdx.x, wid = t >> 6, l = t & 63, c = l & 15, g = l >> 4;
    const int gz = blockIdx.z;
    const f16 *Ap, *Bp; const float* bias; int m0, n0;
    if (gz == 2) { Ap = WvT; Bp = Xv; bias = bv; m0 = blockIdx.x * 128; n0 = blockIdx.y * 128; }
    else if (gz == 1) { Ap = Xk; Bp = WkT; bias = bk; m0 = blockIdx.y * 128; n0 = blockIdx.x * 128; }
    else { Ap = Xq; Bp = WqT; bias = bq; m0 = blockIdx.y * 128; n0 = blockIdx.x * 128; }
    const int wm = wid >> 1, wn = wid & 1;
    f32x4 acc[4][4] = {};
    char* AsB = (char*)As; char* BsB = (char*)Bs;

    for (int k0 = 0; k0 < DD; k0 += 64) {
        __syncthreads();
#pragma unroll
        for (int j = 0; j < 4; ++j) {
            int row = wid * 32 + j * 8 + (l >> 3);
            int slot = (l & 7) ^ (row & 7);
            gload16(Ap + (size_t)(m0 + row) * DD + k0 + slot * 8,
                    AsB + (wid * 32 + j * 8) * 128);
            gload16(Bp + (size_t)(n0 + row) * DD + k0 + slot * 8,
                    BsB + (wid * 32 + j * 8) * 128);
        }
        __syncthreads();
#pragma unroll
        for (int ks = 0; ks < 2; ++ks) {
            half8 af[4];
#pragma unroll
            for (int mt = 0; mt < 4; ++mt) {
                int row = wm * 64 + mt * 16 + c;
                af[mt] = *(const half8*)(AsB + row * 128 +
                         ((ks * 64 + g * 16) ^ ((row & 7) << 4)));
            }
#pragma unroll
            for (int nt = 0; nt < 4; ++nt) {
                int row = wn * 64 + nt * 16 + c;
                half8 bf = *(const half8*)(BsB + row * 128 +
                           ((ks * 64 + g * 16) ^ ((row & 7) << 4)));
#pragma unroll
                for (int mt = 0; mt < 4; ++mt)
                    acc[mt][nt] = __builtin_amdgcn_mfma_f32_16x16x32_f16(
                        af[mt], bf, acc[mt][nt], 0, 0, 0);
            }
        }
    }

    const float post = (gz == 0) ? 0.125f * LOG2E : 1.0f;
    if (gz < 2) {
        f16* dst = gz ? Ko : Qo;
#pragma unroll
        for (int nt = 0; nt < 4; ++nt) {
            int n = n0 + wn * 64 + nt * 16 + c;
            float bn = bias[n];
            int h = n >> 6, hd = n & 63;
#pragma unroll
            for (int mt = 0; mt < 4; ++mt)
#pragma unroll
                for (int reg = 0; reg < 4; ++reg) {
                    int m = m0 + wm * 64 + mt * 16 + 4 * g + reg;
                    int b = m >> 11, s = m & (SS - 1);
                    dst[(((size_t)(b * HH + h)) * SS + s) * 64 + hd] =
                        (f16)((acc[mt][nt][reg] + bn) * post);
                }
        }
    } else {
#pragma unroll
        for (int mt = 0; mt < 4; ++mt)
#pragma unroll
            for (int reg = 0; reg < 4; ++reg) {
                int m = m0 + wm * 64 + mt * 16 + 4 * g + reg;   // d index
                float bd = bias[m];
                int h = m >> 6, dl = m & 63;
#pragma unroll
                for (int nt = 0; nt < 4; ++nt) {
                    int n = n0 + wn * 64 + nt * 16 + c;          // s index
                    int b = n >> 11, s = n & (SS - 1);
                    VTo[(((size_t)(b * HH + h)) * 64 + dl) * SS + s] =
                        (f16)(acc[mt][nt][reg] + bd);
                }
            }
    }
}

// ============================================================
// Flash attention, f16 MFMA, base-2 softmax. Block = 64 q-rows of one
// (b,h); 4 waves x 16 rows. K-tiles 64. Bias from rpbT (f16, coalesced);
// mask from 1-MB bit table (uniform u64 loads + VALU select).
// LDS: Qs 8K (shared with f16 P), Ks 8K, Vs 8K = 24 KB.
// ============================================================
__global__ __launch_bounds__(256, 5)
void attn_fwd(const f16* __restrict__ Qw, const f16* __restrict__ Kw,
              const f16* __restrict__ VTw, const f16* __restrict__ rpbT,
              const u64* __restrict__ mbits, f16* __restrict__ AOh)
{
    __shared__ f16 Qs[64 * 64];   // Q staging, then P (f16)
    __shared__ f16 Ks[64 * 64];
    __shared__ f16 Vs[64 * 64];
    char* QsB = (char*)Qs; char* KsB = (char*)Ks; char* VsB = (char*)Vs;

    const int t = threadIdx.x, wid = t >> 6, l = t & 63, c = l & 15, g = l >> 4;
    const int bh = blockIdx.x, b = bh >> 4, h = bh & 15;
    const int q0 = blockIdx.y * 64;
    const size_t baseSD = (size_t)bh * SS * 64;      // Q/K rows base
    const size_t baseDS = (size_t)bh * 64 * SS;      // V^T rows base
    const f16* rpbH = rpbT + (size_t)h * SS * SS;

    // per-reg row pointers (q-row fixed per reg)
    const f16* biasRow[4];
    const u64* mbRow[4];
#pragma unroll
    for (int reg = 0; reg < 4; ++reg) {
        int qrow = q0 + wid * 16 + 4 * g + reg;
        biasRow[reg] = rpbH + (size_t)qrow * SS + c;
        mbRow[reg]   = mbits + ((size_t)b * SS + qrow) * 32;
    }

    // stage Q (64 rows x 64 f16), pre-swizzled source -> linear LDS
#pragma unroll
    for (int j = 0; j < 2; ++j) {
        int row = wid * 16 + j * 8 + (l >> 3);
        int slot = (l & 7) ^ (row & 7);
        gload16(Qw + baseSD + (size_t)(q0 + row) * 64 + slot * 8,
                QsB + (wid * 16 + j * 8) * 128);
    }

    half8 qf[2];
    f32x4 acc_o[4] = {};
    float mrow[4], lp[4];
#pragma unroll
    for (int r = 0; r < 4; ++r) { mrow[r] = -INFINITY; lp[r] = 0.f; }

    for (int kt = 0; kt < SS / 64; ++kt) {
        const int j0 = kt * 64;
        __syncthreads();   // A: prev PV done
        // stage K [key][hd] and V^T [d][key]
#pragma unroll
        for (int j = 0; j < 2; ++j) {
            int row = wid * 16 + j * 8 + (l >> 3);
            int slot = (l & 7) ^ (row & 7);
            gload16(Kw + baseSD + (size_t)(j0 + row) * 64 + slot * 8,
                    KsB + (wid * 16 + j * 8) * 128);
            gload16(VTw + baseDS + (size_t)row * SS + j0 + slot * 8,
                    VsB + (wid * 16 + j * 8) * 128);
        }
        __syncthreads();   // B: K/V staged (Q staged at kt=0 too)
        // issue bias + mask loads now; consumed after QK MFMAs
        f16 bb[4][4];
        u64 mm[4];
#pragma unroll
        for (int reg = 0; reg < 4; ++reg) {
            const f16* p = biasRow[reg] + j0;
#pragma unroll
            for (int nt = 0; nt < 4; ++nt) bb[reg][nt] = p[nt * 16];
            mm[reg] = mbRow[reg][kt];
        }
        if (kt == 0) {
#pragma unroll
            for (int ks = 0; ks < 2; ++ks) {
                int row = wid * 16 + c;
                qf[ks] = *(const half8*)(QsB + row * 128 +
                         ((ks * 64 + g * 16) ^ ((row & 7) << 4)));
            }
        }
        // QK^T (log2-domain scores; Q pre-scaled by 0.125*log2e)
        f32x4 sc[4] = {};
#pragma unroll
        for (int ks = 0; ks < 2; ++ks)
#pragma unroll
            for (int nt = 0; nt < 4; ++nt) {
                int row = nt * 16 + c;
                half8 kf = *(const half8*)(KsB + row * 128 +
                           ((ks * 64 + g * 16) ^ ((row & 7) << 4)));
                sc[nt] = __builtin_amdgcn_mfma_f32_16x16x32_f16(
                    qf[ks], kf, sc[nt], 0, 0, 0);
            }
        // bias/mask + online softmax (base 2), DPP row-max, deferred sum
#pragma unroll
        for (int reg = 0; reg < 4; ++reg) {
            u64 sh = mm[reg] >> c;
            float s0 = sc[0][reg] + ((sh & 1)         ? (float)bb[reg][0] : MASKNEG);
            float s1 = sc[1][reg] + (((sh >> 16) & 1) ? (float)bb[reg][1] : MASKNEG);
            float s2 = sc[2][reg] + (((sh >> 32) & 1) ? (float)bb[reg][2] : MASKNEG);
            float s3 = sc[3][reg] + (((sh >> 48) & 1) ? (float)bb[reg][3] : MASKNEG);
            float rm = fmaxf(fmaxf(s0, s1), fmaxf(s2, s3));
            rm = dpp_max16(rm);
            float mn = fmaxf(mrow[reg], rm);
            float scal = exp2f(mrow[reg] - mn);   // exp2(-inf)=0 first tile
            mrow[reg] = mn;
            float p0 = exp2f(s0 - mn), p1 = exp2f(s1 - mn);
            float p2 = exp2f(s2 - mn), p3 = exp2f(s3 - mn);
            sc[0][reg] = p0; sc[1][reg] = p1;
            sc[2][reg] = p2; sc[3][reg] = p3;
            lp[reg] = lp[reg] * scal + (p0 + p1 + p2 + p3);
#pragma unroll
            for (int nt = 0; nt < 4; ++nt) acc_o[nt][reg] *= scal;
        }
        // write P as f16 into Qs region (swizzled); per-wave 16-row band
#pragma unroll
        for (int reg = 0; reg < 4; ++reg) {
            int qrl = wid * 16 + 4 * g + reg;
            char* pr = QsB + qrl * 128;
            int sw = (qrl & 7) << 4;
#pragma unroll
            for (int nt = 0; nt < 4; ++nt)
                *(f16*)(pr + ((nt * 32 + c * 2) ^ sw)) = (f16)sc[nt][reg];
        }
        __syncthreads();   // C: P ready
        // PV: acc_o += P @ V
#pragma unroll
        for (int ks = 0; ks < 2; ++ks) {
            int prow = wid * 16 + c;
            half8 pa = *(const half8*)(QsB + prow * 128 +
                       ((ks * 64 + g * 16) ^ ((prow & 7) << 4)));
#pragma unroll
            for (int nt = 0; nt < 4; ++nt) {
                int row = nt * 16 + c;
                half8 vf = *(const half8*)(VsB + row * 128 +
                           ((ks * 64 + g * 16) ^ ((row & 7) << 4)));
                acc_o[nt] = __builtin_amdgcn_mfma_f32_16x16x32_f16(
                    pa, vf, acc_o[nt], 0, 0, 0);
            }
        }
    }
    // epilogue: reduce deferred sums, normalize, store f16 AO
#pragma unroll
    for (int reg = 0; reg < 4; ++reg) {
        float lrow = dpp_sum16(lp[reg]);
        float inv = 1.0f / lrow;
        int qrow = q0 + wid * 16 + 4 * g + reg;
#pragma unroll
        for (int nt = 0; nt < 4; ++nt)
            AOh[((size_t)b * SS + qrow) * DD + h * 64 + nt * 16 + c] =
                (f16)(acc_o[nt][reg] * inv);
    }
}

// ============================================================
// Output projection: out(f32) = AO(f16) @ Wo + bo.
// ============================================================
__global__ __launch_bounds__(256)
void gemm_out(const f16* __restrict__ A, const f16* __restrict__ BT,
              const float* __restrict__ bias, float* __restrict__ out)
{
    __shared__ f16 As[128 * 64];
    __shared__ f16 Bs[128 * 64];
    const int t = threadIdx.x, wid = t >> 6, l = t & 63, c = l & 15, g = l >> 4;
    const int m0 = blockIdx.y * 128, n0 = blockIdx.x * 128;
    const int wm = wid >> 1, wn = wid & 1;
    f32x4 acc[4][4] = {};
    char* AsB = (char*)As; char* BsB = (char*)Bs;

    for (int k0 = 0; k0 < DD; k0 += 64) {
        __syncthreads();
#pragma unroll
        for (int j = 0; j < 4; ++j) {
            int row = wid * 32 + j * 8 + (l >> 3);
            int slot = (l & 7) ^ (row & 7);
            gload16(A + (size_t)(m0 + row) * DD + k0 + slot * 8,
                    AsB + (wid * 32 + j * 8) * 128);
            gload16(BT + (size_t)(n0 + row) * DD + k0 + slot * 8,
                    BsB + (wid * 32 + j * 8) * 128);
        }
        __syncthreads();
#pragma unroll
        for (int ks = 0; ks < 2; ++ks) {
            half8 af[4];
#pragma unroll
            for (int mt = 0; mt < 4; ++mt) {
                int row = wm * 64 + mt * 16 + c;
                af[mt] = *(const half8*)(AsB + row * 128 +
                         ((ks * 64 + g * 16) ^ ((row & 7) << 4)));
            }
#pragma unroll
            for (int nt = 0; nt < 4; ++nt) {
                int row = wn * 64 + nt * 16 + c;
                half8 bf = *(const half8*)(BsB + row * 128 +
                           ((ks * 64 + g * 16) ^ ((row & 7) << 4)));
#pragma unroll
                for (int mt = 0; mt < 4; ++mt)
                    acc[mt][nt] = __builtin_amdgcn_mfma_f32_16x16x32_f16(
                        af[mt], bf, acc[mt][nt], 0, 0, 0);
            }
        }
    }
#pragma unroll
    for (int nt = 0; nt < 4; ++nt) {
        int n = n0 + wn * 64 + nt * 16 + c;
        float bn = bias[n];
#pragma unroll
        for (int mt = 0; mt < 4; ++mt)
#pragma unroll
            for (int reg = 0; reg < 4; ++reg) {
                int m = m0 + wm * 64 + mt * 16 + 4 * g + reg;
                out[(size_t)m * DD + n] = acc[mt][nt][reg] + bn;
            }
    }
}

extern "C" void kernel_launch(void* const* d_in, const int* in_sizes, int n_in,
                              void* d_out, int out_size, void* d_ws, size_t ws_size,
                              hipStream_t stream)
{
    (void)in_sizes; (void)n_in; (void)out_size; (void)ws_size;

    const float* query = (const float*)d_in[0];
    const float* key   = (const float*)d_in[1];
    const float* value = (const float*)d_in[2];
    const int*   mask  = (const int*)d_in[3];
    const float* rpb   = (const float*)d_in[4];
    const float* Wq = (const float*)d_in[5];  const float* bq = (const float*)d_in[6];
    const float* Wk = (const float*)d_in[7];  const float* bk = (const float*)d_in[8];
    const float* Wv = (const float*)d_in[9];  const float* bv = (const float*)d_in[10];
    const float* Wo = (const float*)d_in[11]; const float* bo = (const float*)d_in[12];
    float* out = (float*)d_out;

    // workspace layout (f16 elements). AOh aliases Xq (dead after proj3).
    const size_t NX = (size_t)2 * SS * DD;   // 4096x1024
    const size_t NW = (size_t)DD * DD;       // 1024x1024
    f16* Xq    = (f16*)d_ws;
    f16* Xk    = Xq + NX;
    f16* Xv    = Xk + NX;
    f16* WqT   = Xv + NX;
    f16* WkT   = WqT + NW;
    f16* WvT   = WkT + NW;
    f16* WoT   = WvT + NW;
    f16* Qw    = WoT + NW;
    f16* Kw    = Qw + NX;
    f16* VTw   = Kw + NX;
    f16* rpbT  = VTw + NX;                   // 16*2048*2048 f16 = 128 MB
    u64* mbits = (u64*)(rpbT + (size_t)HH * SS * SS);  // 1 MB
    f16* AOh   = Xq;   // alias

    cvt_x<<<dim3(NX / 2048, 1, 3), 256, 0, stream>>>(query, key, value, Xq, Xk, Xv);
    cvt_wT<<<dim3(16, 16, 4), 256, 0, stream>>>(Wq, Wk, Wv, Wo, WqT, WkT, WvT, WoT);
    cvt_rpbT<<<dim3(SS / 16, SS / 64), 256, 0, stream>>>(rpb, rpbT);
    cvt_maskbits<<<dim3((2 * SS) / 4), 256, 0, stream>>>(mask, mbits);
    proj3<<<dim3(8, 32, 3), 256, 0, stream>>>(Xq, Xk, Xv, WqT, WkT, WvT,
                                              bq, bk, bv, Qw, Kw, VTw);
    attn_fwd<<<dim3(2 * HH, SS / 64), 256, 0, stream>>>(Qw, Kw, VTw, rpbT, mbits, AOh);
    gemm_out<<<dim3(8, 32), 256, 0, stream>>>(AOh, WoT, bo, out);
}

// Round 6
// 332.350 us; speedup vs baseline: 1.9042x; 1.3297x over previous
//
#include <hip/hip_runtime.h>
#include <math.h>

#define SS 2048
#define DD 1024
#define HH 16

typedef _Float16 f16;
typedef _Float16 half8 __attribute__((ext_vector_type(8)));
typedef float f32x4 __attribute__((ext_vector_type(4)));
typedef unsigned long long u64;

#define LOG2E 1.44269504f
#define MASKNEG -30000.0f

__device__ __forceinline__ void gload16(const void* g, void* lds) {
    __builtin_amdgcn_global_load_lds(
        (const __attribute__((address_space(1))) unsigned int*)g,
        (__attribute__((address_space(3))) unsigned int*)lds, 16, 0, 0);
}

// DPP 16-lane reductions (VALU pipe, no LDS traffic).
__device__ __forceinline__ float dpp_max16(float x) {
    float y;
    y = __uint_as_float(__builtin_amdgcn_mov_dpp(__float_as_uint(x), 0xB1, 0xF, 0xF, false));
    x = fmaxf(x, y);
    y = __uint_as_float(__builtin_amdgcn_mov_dpp(__float_as_uint(x), 0x4E, 0xF, 0xF, false));
    x = fmaxf(x, y);
    y = __uint_as_float(__builtin_amdgcn_mov_dpp(__float_as_uint(x), 0x124, 0xF, 0xF, false));
    x = fmaxf(x, y);
    y = __uint_as_float(__builtin_amdgcn_mov_dpp(__float_as_uint(x), 0x128, 0xF, 0xF, false));
    x = fmaxf(x, y);
    return x;
}
__device__ __forceinline__ float dpp_sum16(float x) {
    float y;
    y = __uint_as_float(__builtin_amdgcn_mov_dpp(__float_as_uint(x), 0xB1, 0xF, 0xF, false));
    x += y;
    y = __uint_as_float(__builtin_amdgcn_mov_dpp(__float_as_uint(x), 0x4E, 0xF, 0xF, false));
    x += y;
    y = __uint_as_float(__builtin_amdgcn_mov_dpp(__float_as_uint(x), 0x124, 0xF, 0xF, false));
    x += y;
    y = __uint_as_float(__builtin_amdgcn_mov_dpp(__float_as_uint(x), 0x128, 0xF, 0xF, false));
    x += y;
    return x;
}

// ============================================================
// prep 1: f32 -> f16 elementwise for query/key/value
// ============================================================
__global__ __launch_bounds__(256)
void cvt_x(const float* __restrict__ q, const float* __restrict__ k,
           const float* __restrict__ v, f16* __restrict__ oq,
           f16* __restrict__ ok, f16* __restrict__ ov)
{
    const int z = blockIdx.z;
    const float* src = z == 0 ? q : z == 1 ? k : v;
    f16* dst = z == 0 ? oq : z == 1 ? ok : ov;
    size_t i = ((size_t)blockIdx.x * 256 + threadIdx.x) * 8;
    float4 v0 = *reinterpret_cast<const float4*>(src + i);
    float4 v1 = *reinterpret_cast<const float4*>(src + i + 4);
    half8 h;
    h[0] = (f16)v0.x; h[1] = (f16)v0.y; h[2] = (f16)v0.z; h[3] = (f16)v0.w;
    h[4] = (f16)v1.x; h[5] = (f16)v1.y; h[6] = (f16)v1.z; h[7] = (f16)v1.w;
    *reinterpret_cast<half8*>(dst + i) = h;
}

// ============================================================
// prep 2: W (k,n) f32 -> WT (n,k) f16, 64x64 tiles through LDS
// ============================================================
__global__ __launch_bounds__(256)
void cvt_wT(const float* __restrict__ wq, const float* __restrict__ wk,
            const float* __restrict__ wv, const float* __restrict__ wo,
            f16* __restrict__ oq, f16* __restrict__ ok,
            f16* __restrict__ ov, f16* __restrict__ oo)
{
    __shared__ float Lt[64][65];
    const int z = blockIdx.z;
    const float* W = z == 0 ? wq : z == 1 ? wk : z == 2 ? wv : wo;
    f16* WT = z == 0 ? oq : z == 1 ? ok : z == 2 ? ov : oo;
    const int n0 = blockIdx.x * 64, k0 = blockIdx.y * 64;
    const int t = threadIdx.x;
    {
        int row = t >> 2;               // k-local
        int c0  = (t & 3) * 16;         // n-local
#pragma unroll
        for (int u = 0; u < 4; ++u) {
            float4 x = *reinterpret_cast<const float4*>(
                &W[(size_t)(k0 + row) * DD + n0 + c0 + u * 4]);
            Lt[row][c0 + u * 4 + 0] = x.x;
            Lt[row][c0 + u * 4 + 1] = x.y;
            Lt[row][c0 + u * 4 + 2] = x.z;
            Lt[row][c0 + u * 4 + 3] = x.w;
        }
    }
    __syncthreads();
    {
        int n  = t >> 2;                // n-local
        int kc = (t & 3) * 16;          // k-local chunk
        half8 h0, h1;
#pragma unroll
        for (int u = 0; u < 8; ++u) h0[u] = (f16)Lt[kc + u][n];
#pragma unroll
        for (int u = 0; u < 8; ++u) h1[u] = (f16)Lt[kc + 8 + u][n];
        f16* dst = &WT[(size_t)(n0 + n) * DD + k0 + kc];
        *reinterpret_cast<half8*>(dst) = h0;
        *reinterpret_cast<half8*>(dst + 8) = h1;
    }
}

// ============================================================
// prep 3: rpb[j][i][h] f32 -> rpbT[h][i][j] f16 (scaled log2e).
// LDS-tiled transpose: block = 16 i x 64 j x all 16 h.
// ============================================================
__global__ __launch_bounds__(256)
void cvt_rpbT(const float* __restrict__ rpb, f16* __restrict__ rpbT)
{
    __shared__ f16 Lt[16][16][66];   // [h][i][j], +2 pad
    const int t = threadIdx.x, wid = t >> 6, l = t & 63;
    const int i0 = blockIdx.x * 16;
    const int j0 = blockIdx.y * 64;
    const int il = l >> 2;
    const int h0 = (l & 3) * 4;
#pragma unroll
    for (int p = 0; p < 16; ++p) {
        int jl = p * 4 + wid;
        float4 v = *reinterpret_cast<const float4*>(
            rpb + ((size_t)(j0 + jl) * SS + i0 + il) * HH + h0);
        Lt[h0 + 0][il][jl] = (f16)(v.x * LOG2E);
        Lt[h0 + 1][il][jl] = (f16)(v.y * LOG2E);
        Lt[h0 + 2][il][jl] = (f16)(v.z * LOG2E);
        Lt[h0 + 3][il][jl] = (f16)(v.w * LOG2E);
    }
    __syncthreads();
    const int part = t & 7;
#pragma unroll
    for (int p = 0; p < 8; ++p) {
        int rowid = p * 32 + (t >> 3);
        int h = rowid >> 4, i2 = rowid & 15;
        half8 v = *reinterpret_cast<const half8*>(&Lt[h][i2][part * 8]);
        *reinterpret_cast<half8*>(
            rpbT + ((size_t)h * SS + i0 + i2) * SS + j0 + part * 8) = v;
    }
}

// ============================================================
// prep 4: mask int32 -> bitmask u64[b*SS+i][j/64] via wave ballot.
// ============================================================
__global__ __launch_bounds__(256)
void cvt_maskbits(const int* __restrict__ mask, u64* __restrict__ mb)
{
    const int t = threadIdx.x, wid = t >> 6, l = t & 63;
    const int row = blockIdx.x * 4 + wid;     // b*SS+i
    const int* src = mask + (size_t)row * SS;
    u64* dst = mb + (size_t)row * 32;
    for (int it = 0; it < 32; ++it) {
        int mv = src[it * 64 + l];
        u64 bal = __ballot(mv != 0);
        if (l == 0) dst[it] = bal;
    }
}

// ============================================================
// Fused Q/K/V projection GEMM, f16 MFMA 16x16x32, 128x128 tile BK=64.
// ============================================================
__global__ __launch_bounds__(256)
void proj3(const f16* __restrict__ Xq, const f16* __restrict__ Xk,
           const f16* __restrict__ Xv, const f16* __restrict__ WqT,
           const f16* __restrict__ WkT, const f16* __restrict__ WvT,
           const float* __restrict__ bq, const float* __restrict__ bk,
           const float* __restrict__ bv,
           f16* __restrict__ Qo, f16* __restrict__ Ko, f16* __restrict__ VTo)
{
    __shared__ f16 As[128 * 64];
    __shared__ f16 Bs[128 * 64];
    const int t = threadIdx.x, wid = t >> 6, l = t & 63, c = l & 15, g = l >> 4;
    const int gz = blockIdx.z;
    const f16 *Ap, *Bp; const float* bias; int m0, n0;
    if (gz == 2) { Ap = WvT; Bp = Xv; bias = bv; m0 = blockIdx.x * 128; n0 = blockIdx.y * 128; }
    else if (gz == 1) { Ap = Xk; Bp = WkT; bias = bk; m0 = blockIdx.y * 128; n0 = blockIdx.x * 128; }
    else { Ap = Xq; Bp = WqT; bias = bq; m0 = blockIdx.y * 128; n0 = blockIdx.x * 128; }
    const int wm = wid >> 1, wn = wid & 1;
    f32x4 acc[4][4] = {};
    char* AsB = (char*)As; char* BsB = (char*)Bs;

    for (int k0 = 0; k0 < DD; k0 += 64) {
        __syncthreads();
#pragma unroll
        for (int j = 0; j < 4; ++j) {
            int row = wid * 32 + j * 8 + (l >> 3);
            int slot = (l & 7) ^ (row & 7);
            gload16(Ap + (size_t)(m0 + row) * DD + k0 + slot * 8,
                    AsB + (wid * 32 + j * 8) * 128);
            gload16(Bp + (size_t)(n0 + row) * DD + k0 + slot * 8,
                    BsB + (wid * 32 + j * 8) * 128);
        }
        __syncthreads();
#pragma unroll
        for (int ks = 0; ks < 2; ++ks) {
            half8 af[4];
#pragma unroll
            for (int mt = 0; mt < 4; ++mt) {
                int row = wm * 64 + mt * 16 + c;
                af[mt] = *(const half8*)(AsB + row * 128 +
                         ((ks * 64 + g * 16) ^ ((row & 7) << 4)));
            }
#pragma unroll
            for (int nt = 0; nt < 4; ++nt) {
                int row = wn * 64 + nt * 16 + c;
                half8 bf = *(const half8*)(BsB + row * 128 +
                           ((ks * 64 + g * 16) ^ ((row & 7) << 4)));
#pragma unroll
                for (int mt = 0; mt < 4; ++mt)
                    acc[mt][nt] = __builtin_amdgcn_mfma_f32_16x16x32_f16(
                        af[mt], bf, acc[mt][nt], 0, 0, 0);
            }
        }
    }

    const float post = (gz == 0) ? 0.125f * LOG2E : 1.0f;
    if (gz < 2) {
        f16* dst = gz ? Ko : Qo;
#pragma unroll
        for (int nt = 0; nt < 4; ++nt) {
            int n = n0 + wn * 64 + nt * 16 + c;
            float bn = bias[n];
            int h = n >> 6, hd = n & 63;
#pragma unroll
            for (int mt = 0; mt < 4; ++mt)
#pragma unroll
                for (int reg = 0; reg < 4; ++reg) {
                    int m = m0 + wm * 64 + mt * 16 + 4 * g + reg;
                    int b = m >> 11, s = m & (SS - 1);
                    dst[(((size_t)(b * HH + h)) * SS + s) * 64 + hd] =
                        (f16)((acc[mt][nt][reg] + bn) * post);
                }
        }
    } else {
#pragma unroll
        for (int mt = 0; mt < 4; ++mt)
#pragma unroll
            for (int reg = 0; reg < 4; ++reg) {
                int m = m0 + wm * 64 + mt * 16 + 4 * g + reg;   // d index
                float bd = bias[m];
                int h = m >> 6, dl = m & 63;
#pragma unroll
                for (int nt = 0; nt < 4; ++nt) {
                    int n = n0 + wn * 64 + nt * 16 + c;          // s index
                    int b = n >> 11, s = n & (SS - 1);
                    VTo[(((size_t)(b * HH + h)) * 64 + dl) * SS + s] =
                        (f16)(acc[mt][nt][reg] + bd);
                }
            }
    }
}

// ============================================================
// Flash attention, f16 MFMA, base-2 softmax, software-pipelined:
// at iter t, K/V/bias/mask for tile t+1 are loaded into REGISTERS,
// tile t is computed from LDS buf, then regs are ds_written to buf^1
// (compiler's vmcnt wait lands here, after a full compute phase of
// latency hiding) and ONE __syncthreads ends the iteration.
// LDS: Qs 8K (Q then per-wave P bands), Ks 2x8K, Vs 2x8K = 40 KB.
// ============================================================
__global__ __launch_bounds__(256, 4)
void attn_fwd(const f16* __restrict__ Qw, const f16* __restrict__ Kw,
              const f16* __restrict__ VTw, const f16* __restrict__ rpbT,
              const u64* __restrict__ mbits, f16* __restrict__ AOh)
{
    __shared__ f16 Qs[64 * 64];        // Q staging, then P (f16, per-wave)
    __shared__ f16 Ks[2][64 * 64];
    __shared__ f16 Vs[2][64 * 64];
    char* QsB = (char*)Qs;

    const int t = threadIdx.x, wid = t >> 6, l = t & 63, c = l & 15, g = l >> 4;
    const int bh = blockIdx.x, b = bh >> 4, h = bh & 15;
    const int q0 = blockIdx.y * 64;
    const size_t baseSD = (size_t)bh * SS * 64;      // Q/K rows base
    const size_t baseDS = (size_t)bh * 64 * SS;      // V^T rows base
    const f16* Kbase = Kw + baseSD;
    const f16* Vbase = VTw + baseDS;
    const f16* rpbH = rpbT + (size_t)h * SS * SS;

    // per-reg row pointers (q-row fixed per reg)
    const f16* biasRow[4];
    const u64* mbRow[4];
#pragma unroll
    for (int reg = 0; reg < 4; ++reg) {
        int qrow = q0 + wid * 16 + 4 * g + reg;
        biasRow[reg] = rpbH + (size_t)qrow * SS + c;
        mbRow[reg]   = mbits + ((size_t)b * SS + qrow) * 32;
    }

    // staging geometry: per thread rows srow0, srow0+8; 16B chunk.
    // LDS[row][x ^ swz] = G[row][x]  (same image as pre-swizzled gload16)
    const int srow0 = wid * 16 + (l >> 3);
    const int ke    = (l & 7) * 8;                   // element offset in row
    const int sswz  = (srow0 & 7) << 4;              // same for srow0+8
    const int sdst  = ((l & 7) << 4) ^ sswz;         // swizzled byte offset

    // ---- prologue ----
    // Q (64x64 f16) via gload16; each wave stages and later reads ONLY its
    // own 16-row band, so the first __syncthreads' vmcnt drain covers it.
#pragma unroll
    for (int j = 0; j < 2; ++j) {
        int row = wid * 16 + j * 8 + (l >> 3);
        int slot = (l & 7) ^ (row & 7);
        gload16(Qw + baseSD + (size_t)(q0 + row) * 64 + slot * 8,
                QsB + (wid * 16 + j * 8) * 128);
    }
    // K/V tile 0 -> regs -> LDS buf 0
    {
        half8 k0 = *(const half8*)(Kbase + (size_t)srow0 * 64 + ke);
        half8 k1 = *(const half8*)(Kbase + (size_t)(srow0 + 8) * 64 + ke);
        half8 v0 = *(const half8*)(Vbase + (size_t)srow0 * SS + ke);
        half8 v1 = *(const half8*)(Vbase + (size_t)(srow0 + 8) * SS + ke);
        char* kd = (char*)Ks[0]; char* vd = (char*)Vs[0];
        *(half8*)(kd + srow0 * 128 + sdst) = k0;
        *(half8*)(kd + (srow0 + 8) * 128 + sdst) = k1;
        *(half8*)(vd + srow0 * 128 + sdst) = v0;
        *(half8*)(vd + (srow0 + 8) * 128 + sdst) = v1;
    }
    // bias/mask tile 0
    f16 bb[4][4]; u64 mm[4];
#pragma unroll
    for (int reg = 0; reg < 4; ++reg) {
#pragma unroll
        for (int nt = 0; nt < 4; ++nt) bb[reg][nt] = biasRow[reg][nt * 16];
        mm[reg] = mbRow[reg][0];
    }
    __syncthreads();

    half8 qf[2];
    f32x4 acc_o[4] = {};
    float mrow[4], lp[4];
#pragma unroll
    for (int r = 0; r < 4; ++r) { mrow[r] = -INFINITY; lp[r] = 0.f; }

    int buf = 0;
    for (int kt = 0; kt < SS / 64; ++kt) {
        const bool more = (kt + 1 < SS / 64);
        const int jn = more ? (kt + 1) * 64 : 0;     // clamped (safe re-read)
        const int ktn = more ? kt + 1 : 0;

        // ---- issue next-tile loads (registers; latency hidden by compute)
        half8 k0n = *(const half8*)(Kbase + (size_t)(jn + srow0) * 64 + ke);
        half8 k1n = *(const half8*)(Kbase + (size_t)(jn + srow0 + 8) * 64 + ke);
        half8 v0n = *(const half8*)(Vbase + (size_t)srow0 * SS + jn + ke);
        half8 v1n = *(const half8*)(Vbase + (size_t)(srow0 + 8) * SS + jn + ke);
        f16 bbn[4][4]; u64 mmn[4];
#pragma unroll
        for (int reg = 0; reg < 4; ++reg) {
#pragma unroll
            for (int nt = 0; nt < 4; ++nt) bbn[reg][nt] = biasRow[reg][jn + nt * 16];
            mmn[reg] = mbRow[reg][ktn];
        }

        char* KsB = (char*)Ks[buf];
        char* VsB = (char*)Vs[buf];
        if (kt == 0) {
#pragma unroll
            for (int ks = 0; ks < 2; ++ks) {
                int row = wid * 16 + c;
                qf[ks] = *(const half8*)(QsB + row * 128 +
                         ((ks * 64 + g * 16) ^ ((row & 7) << 4)));
            }
        }
        // ---- QK^T (log2-domain scores; Q pre-scaled by 0.125*log2e)
        f32x4 sc[4] = {};
#pragma unroll
        for (int ks = 0; ks < 2; ++ks)
#pragma unroll
            for (int nt = 0; nt < 4; ++nt) {
                int row = nt * 16 + c;
                half8 kf = *(const half8*)(KsB + row * 128 +
                           ((ks * 64 + g * 16) ^ ((row & 7) << 4)));
                sc[nt] = __builtin_amdgcn_mfma_f32_16x16x32_f16(
                    qf[ks], kf, sc[nt], 0, 0, 0);
            }
        // ---- bias/mask + online softmax (base 2), DPP row-max, deferred sum
#pragma unroll
        for (int reg = 0; reg < 4; ++reg) {
            u64 sh = mm[reg] >> c;
            float s0 = sc[0][reg] + ((sh & 1)         ? (float)bb[reg][0] : MASKNEG);
            float s1 = sc[1][reg] + (((sh >> 16) & 1) ? (float)bb[reg][1] : MASKNEG);
            float s2 = sc[2][reg] + (((sh >> 32) & 1) ? (float)bb[reg][2] : MASKNEG);
            float s3 = sc[3][reg] + (((sh >> 48) & 1) ? (float)bb[reg][3] : MASKNEG);
            float rm = fmaxf(fmaxf(s0, s1), fmaxf(s2, s3));
            rm = dpp_max16(rm);
            float mn = fmaxf(mrow[reg], rm);
            float scal = exp2f(mrow[reg] - mn);   // exp2(-inf)=0 first tile
            mrow[reg] = mn;
            float p0 = exp2f(s0 - mn), p1 = exp2f(s1 - mn);
            float p2 = exp2f(s2 - mn), p3 = exp2f(s3 - mn);
            sc[0][reg] = p0; sc[1][reg] = p1;
            sc[2][reg] = p2; sc[3][reg] = p3;
            lp[reg] = lp[reg] * scal + (p0 + p1 + p2 + p3);
#pragma unroll
            for (int nt = 0; nt < 4; ++nt) acc_o[nt][reg] *= scal;
        }
        // ---- write P f16 into Qs region (per-wave 16-row band; no barrier)
#pragma unroll
        for (int reg = 0; reg < 4; ++reg) {
            int qrl = wid * 16 + 4 * g + reg;
            char* pr = QsB + qrl * 128;
            int sw = (qrl & 7) << 4;
#pragma unroll
            for (int nt = 0; nt < 4; ++nt)
                *(f16*)(pr + ((nt * 32 + c * 2) ^ sw)) = (f16)sc[nt][reg];
        }
        // ---- PV: acc_o += P @ V   (P read is same-wave; lgkm handled)
#pragma unroll
        for (int ks = 0; ks < 2; ++ks) {
            int prow = wid * 16 + c;
            half8 pa = *(const half8*)(QsB + prow * 128 +
                       ((ks * 64 + g * 16) ^ ((prow & 7) << 4)));
#pragma unroll
            for (int nt = 0; nt < 4; ++nt) {
                int row = nt * 16 + c;
                half8 vf = *(const half8*)(VsB + row * 128 +
                           ((ks * 64 + g * 16) ^ ((row & 7) << 4)));
                acc_o[nt] = __builtin_amdgcn_mfma_f32_16x16x32_f16(
                    pa, vf, acc_o[nt], 0, 0, 0);
            }
        }
        // ---- commit next tile: regs -> LDS buf^1 (vmcnt wait lands here)
        if (more) {
            char* kd = (char*)Ks[buf ^ 1];
            char* vd = (char*)Vs[buf ^ 1];
            *(half8*)(kd + srow0 * 128 + sdst) = k0n;
            *(half8*)(kd + (srow0 + 8) * 128 + sdst) = k1n;
            *(half8*)(vd + srow0 * 128 + sdst) = v0n;
            *(half8*)(vd + (srow0 + 8) * 128 + sdst) = v1n;
            buf ^= 1;
#pragma unroll
            for (int reg = 0; reg < 4; ++reg) {
#pragma unroll
                for (int nt = 0; nt < 4; ++nt) bb[reg][nt] = bbn[reg][nt];
                mm[reg] = mmn[reg];
            }
        }
        __syncthreads();   // one barrier per iteration
    }
    // epilogue: reduce deferred sums, normalize, store f16 AO
#pragma unroll
    for (int reg = 0; reg < 4; ++reg) {
        float lrow = dpp_sum16(lp[reg]);
        float inv = 1.0f / lrow;
        int qrow = q0 + wid * 16 + 4 * g + reg;
#pragma unroll
        for (int nt = 0; nt < 4; ++nt)
            AOh[((size_t)b * SS + qrow) * DD + h * 64 + nt * 16 + c] =
                (f16)(acc_o[nt][reg] * inv);
    }
}

// ============================================================
// Output projection: out(f32) = AO(f16) @ Wo + bo.
// ============================================================
__global__ __launch_bounds__(256)
void gemm_out(const f16* __restrict__ A, const f16* __restrict__ BT,
              const float* __restrict__ bias, float* __restrict__ out)
{
    __shared__ f16 As[128 * 64];
    __shared__ f16 Bs[128 * 64];
    const int t = threadIdx.x, wid = t >> 6, l = t & 63, c = l & 15, g = l >> 4;
    const int m0 = blockIdx.y * 128, n0 = blockIdx.x * 128;
    const int wm = wid >> 1, wn = wid & 1;
    f32x4 acc[4][4] = {};
    char* AsB = (char*)As; char* BsB = (char*)Bs;

    for (int k0 = 0; k0 < DD; k0 += 64) {
        __syncthreads();
#pragma unroll
        for (int j = 0; j < 4; ++j) {
            int row = wid * 32 + j * 8 + (l >> 3);
            int slot = (l & 7) ^ (row & 7);
            gload16(A + (size_t)(m0 + row) * DD + k0 + slot * 8,
                    AsB + (wid * 32 + j * 8) * 128);
            gload16(BT + (size_t)(n0 + row) * DD + k0 + slot * 8,
                    BsB + (wid * 32 + j * 8) * 128);
        }
        __syncthreads();
#pragma unroll
        for (int ks = 0; ks < 2; ++ks) {
            half8 af[4];
#pragma unroll
            for (int mt = 0; mt < 4; ++mt) {
                int row = wm * 64 + mt * 16 + c;
                af[mt] = *(const half8*)(AsB + row * 128 +
                         ((ks * 64 + g * 16) ^ ((row & 7) << 4)));
            }
#pragma unroll
            for (int nt = 0; nt < 4; ++nt) {
                int row = wn * 64 + nt * 16 + c;
                half8 bf = *(const half8*)(BsB + row * 128 +
                           ((ks * 64 + g * 16) ^ ((row & 7) << 4)));
#pragma unroll
                for (int mt = 0; mt < 4; ++mt)
                    acc[mt][nt] = __builtin_amdgcn_mfma_f32_16x16x32_f16(
                        af[mt], bf, acc[mt][nt], 0, 0, 0);
            }
        }
    }
#pragma unroll
    for (int nt = 0; nt < 4; ++nt) {
        int n = n0 + wn * 64 + nt * 16 + c;
        float bn = bias[n];
#pragma unroll
        for (int mt = 0; mt < 4; ++mt)
#pragma unroll
            for (int reg = 0; reg < 4; ++reg) {
                int m = m0 + wm * 64 + mt * 16 + 4 * g + reg;
                out[(size_t)m * DD + n] = acc[mt][nt][reg] + bn;
            }
    }
}

extern "C" void kernel_launch(void* const* d_in, const int* in_sizes, int n_in,
                              void* d_out, int out_size, void* d_ws, size_t ws_size,
                              hipStream_t stream)
{
    (void)in_sizes; (void)n_in; (void)out_size; (void)ws_size;

    const float* query = (const float*)d_in[0];
    const float* key   = (const float*)d_in[1];
    const float* value = (const float*)d_in[2];
    const int*   mask  = (const int*)d_in[3];
    const float* rpb   = (const float*)d_in[4];
    const float* Wq = (const float*)d_in[5];  const float* bq = (const float*)d_in[6];
    const float* Wk = (const float*)d_in[7];  const float* bk = (const float*)d_in[8];
    const float* Wv = (const float*)d_in[9];  const float* bv = (const float*)d_in[10];
    const float* Wo = (const float*)d_in[11]; const float* bo = (const float*)d_in[12];
    float* out = (float*)d_out;

    // workspace layout (f16 elements). AOh aliases Xq (dead after proj3).
    const size_t NX = (size_t)2 * SS * DD;   // 4096x1024
    const size_t NW = (size_t)DD * DD;       // 1024x1024
    f16* Xq    = (f16*)d_ws;
    f16* Xk    = Xq + NX;
    f16* Xv    = Xk + NX;
    f16* WqT   = Xv + NX;
    f16* WkT   = WqT + NW;
    f16* WvT   = WkT + NW;
    f16* WoT   = WvT + NW;
    f16* Qw    = WoT + NW;
    f16* Kw    = Qw + NX;
    f16* VTw   = Kw + NX;
    f16* rpbT  = VTw + NX;                   // 16*2048*2048 f16 = 128 MB
    u64* mbits = (u64*)(rpbT + (size_t)HH * SS * SS);  // 1 MB
    f16* AOh   = Xq;   // alias

    cvt_x<<<dim3(NX / 2048, 1, 3), 256, 0, stream>>>(query, key, value, Xq, Xk, Xv);
    cvt_wT<<<dim3(16, 16, 4), 256, 0, stream>>>(Wq, Wk, Wv, Wo, WqT, WkT, WvT, WoT);
    cvt_rpbT<<<dim3(SS / 16, SS / 64), 256, 0, stream>>>(rpb, rpbT);
    cvt_maskbits<<<dim3((2 * SS) / 4), 256, 0, stream>>>(mask, mbits);
    proj3<<<dim3(8, 32, 3), 256, 0, stream>>>(Xq, Xk, Xv, WqT, WkT, WvT,
                                              bq, bk, bv, Qw, Kw, VTw);
    attn_fwd<<<dim3(2 * HH, SS / 64), 256, 0, stream>>>(Qw, Kw, VTw, rpbT, mbits, AOh);
    gemm_out<<<dim3(8, 32), 256, 0, stream>>>(AOh, WoT, bo, out);
}

// Round 8
// 297.635 us; speedup vs baseline: 2.1263x; 1.1166x over previous
//
#include <hip/hip_runtime.h>
#include <math.h>

#define SS 2048
#define DD 1024
#define HH 16

typedef _Float16 f16;
typedef _Float16 half8 __attribute__((ext_vector_type(8)));
typedef _Float16 half4 __attribute__((ext_vector_type(4)));
typedef float f32x4 __attribute__((ext_vector_type(4)));
typedef unsigned long long u64;

#define LOG2E 1.44269504f
#define MASKNEG -30000.0f

__device__ __forceinline__ void gload16(const void* g, void* lds) {
    __builtin_amdgcn_global_load_lds(
        (const __attribute__((address_space(1))) unsigned int*)g,
        (__attribute__((address_space(3))) unsigned int*)lds, 16, 0, 0);
}

// ============================================================
// prep 1: f32 -> f16 elementwise for query/key/value
// ============================================================
__global__ __launch_bounds__(256)
void cvt_x(const float* __restrict__ q, const float* __restrict__ k,
           const float* __restrict__ v, f16* __restrict__ oq,
           f16* __restrict__ ok, f16* __restrict__ ov)
{
    const int z = blockIdx.z;
    const float* src = z == 0 ? q : z == 1 ? k : v;
    f16* dst = z == 0 ? oq : z == 1 ? ok : ov;
    size_t i = ((size_t)blockIdx.x * 256 + threadIdx.x) * 8;
    float4 v0 = *reinterpret_cast<const float4*>(src + i);
    float4 v1 = *reinterpret_cast<const float4*>(src + i + 4);
    half8 h;
    h[0] = (f16)v0.x; h[1] = (f16)v0.y; h[2] = (f16)v0.z; h[3] = (f16)v0.w;
    h[4] = (f16)v1.x; h[5] = (f16)v1.y; h[6] = (f16)v1.z; h[7] = (f16)v1.w;
    *reinterpret_cast<half8*>(dst + i) = h;
}

// ============================================================
// prep 2: W (k,n) f32 -> WT (n,k) f16, 64x64 tiles through LDS
// ============================================================
__global__ __launch_bounds__(256)
void cvt_wT(const float* __restrict__ wq, const float* __restrict__ wk,
            const float* __restrict__ wv, const float* __restrict__ wo,
            f16* __restrict__ oq, f16* __restrict__ ok,
            f16* __restrict__ ov, f16* __restrict__ oo)
{
    __shared__ float Lt[64][65];
    const int z = blockIdx.z;
    const float* W = z == 0 ? wq : z == 1 ? wk : z == 2 ? wv : wo;
    f16* WT = z == 0 ? oq : z == 1 ? ok : z == 2 ? ov : oo;
    const int n0 = blockIdx.x * 64, k0 = blockIdx.y * 64;
    const int t = threadIdx.x;
    {
        int row = t >> 2;               // k-local
        int c0  = (t & 3) * 16;         // n-local
#pragma unroll
        for (int u = 0; u < 4; ++u) {
            float4 x = *reinterpret_cast<const float4*>(
                &W[(size_t)(k0 + row) * DD + n0 + c0 + u * 4]);
            Lt[row][c0 + u * 4 + 0] = x.x;
            Lt[row][c0 + u * 4 + 1] = x.y;
            Lt[row][c0 + u * 4 + 2] = x.z;
            Lt[row][c0 + u * 4 + 3] = x.w;
        }
    }
    __syncthreads();
    {
        int n  = t >> 2;                // n-local
        int kc = (t & 3) * 16;          // k-local chunk
        half8 h0, h1;
#pragma unroll
        for (int u = 0; u < 8; ++u) h0[u] = (f16)Lt[kc + u][n];
#pragma unroll
        for (int u = 0; u < 8; ++u) h1[u] = (f16)Lt[kc + 8 + u][n];
        f16* dst = &WT[(size_t)(n0 + n) * DD + k0 + kc];
        *reinterpret_cast<half8*>(dst) = h0;
        *reinterpret_cast<half8*>(dst + 8) = h1;
    }
}

// ============================================================
// prep 3: rpb[j][i][h] f32 -> rpbT3[h][i][j'] f16 (scaled log2e),
// with j permuted WITHIN each 64-block: pos g*16+nt*4+reg holds the
// value for j = nt*16+4g+reg — so the attn kernel's lane (c,g) reads
// its 16 bias values as 2 contiguous half8 loads.
// ============================================================
__global__ __launch_bounds__(256)
void cvt_rpbT3(const float* __restrict__ rpb, f16* __restrict__ rpbT)
{
    __shared__ f16 Lt[16][16][66];   // [h][i][j-local], +2 pad
    const int t = threadIdx.x, wid = t >> 6, l = t & 63;
    const int i0 = blockIdx.x * 16;
    const int j0 = blockIdx.y * 64;
    const int il = l >> 2;
    const int h0 = (l & 3) * 4;
#pragma unroll
    for (int p = 0; p < 16; ++p) {
        int jl = p * 4 + wid;
        float4 v = *reinterpret_cast<const float4*>(
            rpb + ((size_t)(j0 + jl) * SS + i0 + il) * HH + h0);
        Lt[h0 + 0][il][jl] = (f16)(v.x * LOG2E);
        Lt[h0 + 1][il][jl] = (f16)(v.y * LOG2E);
        Lt[h0 + 2][il][jl] = (f16)(v.z * LOG2E);
        Lt[h0 + 3][il][jl] = (f16)(v.w * LOG2E);
    }
    __syncthreads();
    const int part = t & 7;
#pragma unroll
    for (int p = 0; p < 8; ++p) {
        int rowid = p * 32 + (t >> 3);
        int h = rowid >> 4, i2 = rowid & 15;
        half8 v;
#pragma unroll
        for (int e = 0; e < 8; ++e) {
            // out position q = part*8+e = g*16+nt*4+reg -> source j
            int sig = 32 * (part & 1) + 16 * (e >> 2) + 4 * (part >> 1) + (e & 3);
            v[e] = Lt[h][i2][sig];
        }
        *reinterpret_cast<half8*>(
            rpbT + ((size_t)h * SS + i0 + i2) * SS + j0 + part * 8) = v;
    }
}

// ============================================================
// prep 4: mask int32 -> bitmask u64[b*SS+i][j/64] via wave ballot.
// ============================================================
__global__ __launch_bounds__(256)
void cvt_maskbits(const int* __restrict__ mask, u64* __restrict__ mb)
{
    const int t = threadIdx.x, wid = t >> 6, l = t & 63;
    const int row = blockIdx.x * 4 + wid;     // b*SS+i
    const int* src = mask + (size_t)row * SS;
    u64* dst = mb + (size_t)row * 32;
    for (int it = 0; it < 32; ++it) {
        int mv = src[it * 64 + l];
        u64 bal = __ballot(mv != 0);
        if (l == 0) dst[it] = bal;
    }
}

// ============================================================
// Fused Q/K/V projection GEMM, f16 MFMA 16x16x32, 128x128 tile BK=64.
// ============================================================
__global__ __launch_bounds__(256)
void proj3(const f16* __restrict__ Xq, const f16* __restrict__ Xk,
           const f16* __restrict__ Xv, const f16* __restrict__ WqT,
           const f16* __restrict__ WkT, const f16* __restrict__ WvT,
           const float* __restrict__ bq, const float* __restrict__ bk,
           const float* __restrict__ bv,
           f16* __restrict__ Qo, f16* __restrict__ Ko, f16* __restrict__ VTo)
{
    __shared__ f16 As[128 * 64];
    __shared__ f16 Bs[128 * 64];
    const int t = threadIdx.x, wid = t >> 6, l = t & 63, c = l & 15, g = l >> 4;
    const int gz = blockIdx.z;
    const f16 *Ap, *Bp; const float* bias; int m0, n0;
    if (gz == 2) { Ap = WvT; Bp = Xv; bias = bv; m0 = blockIdx.x * 128; n0 = blockIdx.y * 128; }
    else if (gz == 1) { Ap = Xk; Bp = WkT; bias = bk; m0 = blockIdx.y * 128; n0 = blockIdx.x * 128; }
    else { Ap = Xq; Bp = WqT; bias = bq; m0 = blockIdx.y * 128; n0 = blockIdx.x * 128; }
    const int wm = wid >> 1, wn = wid & 1;
    f32x4 acc[4][4] = {};
    char* AsB = (char*)As; char* BsB = (char*)Bs;

    for (int k0 = 0; k0 < DD; k0 += 64) {
        __syncthreads();
#pragma unroll
        for (int j = 0; j < 4; ++j) {
            int row = wid * 32 + j * 8 + (l >> 3);
            int slot = (l & 7) ^ (row & 7);
            gload16(Ap + (size_t)(m0 + row) * DD + k0 + slot * 8,
                    AsB + (wid * 32 + j * 8) * 128);
            gload16(Bp + (size_t)(n0 + row) * DD + k0 + slot * 8,
                    BsB + (wid * 32 + j * 8) * 128);
        }
        __syncthreads();
#pragma unroll
        for (int ks = 0; ks < 2; ++ks) {
            half8 af[4];
#pragma unroll
            for (int mt = 0; mt < 4; ++mt) {
                int row = wm * 64 + mt * 16 + c;
                af[mt] = *(const half8*)(AsB + row * 128 +
                         ((ks * 64 + g * 16) ^ ((row & 7) << 4)));
            }
#pragma unroll
            for (int nt = 0; nt < 4; ++nt) {
                int row = wn * 64 + nt * 16 + c;
                half8 bf = *(const half8*)(BsB + row * 128 +
                           ((ks * 64 + g * 16) ^ ((row & 7) << 4)));
#pragma unroll
                for (int mt = 0; mt < 4; ++mt)
                    acc[mt][nt] = __builtin_amdgcn_mfma_f32_16x16x32_f16(
                        af[mt], bf, acc[mt][nt], 0, 0, 0);
            }
        }
    }

    const float post = (gz == 0) ? 0.125f * LOG2E : 1.0f;
    if (gz < 2) {
        f16* dst = gz ? Ko : Qo;
#pragma unroll
        for (int nt = 0; nt < 4; ++nt) {
            int n = n0 + wn * 64 + nt * 16 + c;
            float bn = bias[n];
            int h = n >> 6, hd = n & 63;
#pragma unroll
            for (int mt = 0; mt < 4; ++mt)
#pragma unroll
                for (int reg = 0; reg < 4; ++reg) {
                    int m = m0 + wm * 64 + mt * 16 + 4 * g + reg;
                    int b = m >> 11, s = m & (SS - 1);
                    dst[(((size_t)(b * HH + h)) * SS + s) * 64 + hd] =
                        (f16)((acc[mt][nt][reg] + bn) * post);
                }
        }
    } else {
#pragma unroll
        for (int mt = 0; mt < 4; ++mt)
#pragma unroll
            for (int reg = 0; reg < 4; ++reg) {
                int m = m0 + wm * 64 + mt * 16 + 4 * g + reg;   // d index
                float bd = bias[m];
                int h = m >> 6, dl = m & 63;
#pragma unroll
                for (int nt = 0; nt < 4; ++nt) {
                    int n = n0 + wn * 64 + nt * 16 + c;          // s index
                    int b = n >> 11, s = n & (SS - 1);
                    VTo[(((size_t)(b * HH + h)) * 64 + dl) * SS + s] =
                        (f16)(acc[mt][nt][reg] + bd);
                }
            }
    }
}

// ============================================================
// Flash attention v3: SWAPPED QK^T (mfma(K,Q)) -> lane-local softmax;
// PV via mfma_f32_16x16x16f16 with P packed in-register (no P LDS).
// V staged with within-32 key permute so PV b128 reads yield both
// half4 operands. Bias: 2 half8 loads (permuted rpbT3) as MFMA C-init;
// mask: 1 u64. Defer-max (THR=8), setprio around MFMA clusters.
// K/V double-buffered reg-staging, one barrier/iter. LDS 32 KB.
// ============================================================
__global__ __launch_bounds__(256, 4)
void attn_fwd(const f16* __restrict__ Qw, const f16* __restrict__ Kw,
              const f16* __restrict__ VTw, const f16* __restrict__ rpbT,
              const u64* __restrict__ mbits, f16* __restrict__ AOh)
{
    __shared__ f16 Ks[2][64 * 64];
    __shared__ f16 Vs[2][64 * 64];

    const int t = threadIdx.x, wid = t >> 6, l = t & 63, c = l & 15, g = l >> 4;
    const int bh = blockIdx.x, b = bh >> 4, h = bh & 15;
    const int q0 = blockIdx.y * 64;
    const size_t baseSD = (size_t)bh * SS * 64;
    const size_t baseDS = (size_t)bh * 64 * SS;
    const f16* Kbase = Kw + baseSD;
    const f16* Vbase = VTw + baseDS;

    const int qrow_c = q0 + wid * 16 + c;            // this lane's softmax row
    const f16* bp = rpbT + (size_t)h * SS * SS + (size_t)qrow_c * SS + g * 16;
    const u64* mp = mbits + ((size_t)b * SS + qrow_c) * 32;

    // staging geometry (per thread: rows srow0, srow0+8; 16B K chunk,
    // V split into 2 permuted half4 chunks)
    const int s     = l & 7;
    const int srow0 = wid * 16 + (l >> 3);
    const int sswz  = (srow0 & 7) << 4;
    const int kdst  = (s << 4) ^ sswz;               // K byte offset in row
    const int velo  = 32 * (s >> 2) + 16 * (s & 1) + 4 * ((s >> 1) & 1);
    const int vdlo  = (velo * 2) ^ sswz;             // V low half4 byte offset
    const int vdhi  = (velo * 2 + 16) ^ sswz;        // V high half4 byte offset

    // bpermute byte-addresses for gathering per-output-row scalars
    int ga[4];
#pragma unroll
    for (int r = 0; r < 4; ++r) ga[r] = (g * 4 + r) * 4;

    // Q fragment: direct global loads (B-operand layout)
    half8 qf[2];
    qf[0] = *(const half8*)(Qw + baseSD + (size_t)qrow_c * 64 + g * 8);
    qf[1] = *(const half8*)(Qw + baseSD + (size_t)qrow_c * 64 + 32 + g * 8);

    // ---- prologue: stage tile 0 ----
    {
        half8 k0 = *(const half8*)(Kbase + (size_t)srow0 * 64 + s * 8);
        half8 k1 = *(const half8*)(Kbase + (size_t)(srow0 + 8) * 64 + s * 8);
        half8 v0 = *(const half8*)(Vbase + (size_t)srow0 * SS + s * 8);
        half8 v1 = *(const half8*)(Vbase + (size_t)(srow0 + 8) * SS + s * 8);
        char* kd = (char*)Ks[0]; char* vd = (char*)Vs[0];
        *(half8*)(kd + srow0 * 128 + kdst) = k0;
        *(half8*)(kd + (srow0 + 8) * 128 + kdst) = k1;
        half4 lo0 = {v0[0], v0[1], v0[2], v0[3]}, hi0 = {v0[4], v0[5], v0[6], v0[7]};
        half4 lo1 = {v1[0], v1[1], v1[2], v1[3]}, hi1 = {v1[4], v1[5], v1[6], v1[7]};
        *(half4*)(vd + srow0 * 128 + vdlo) = lo0;
        *(half4*)(vd + srow0 * 128 + vdhi) = hi0;
        *(half4*)(vd + (srow0 + 8) * 128 + vdlo) = lo1;
        *(half4*)(vd + (srow0 + 8) * 128 + vdhi) = hi1;
    }
    half8 bb0 = *(const half8*)(bp);
    half8 bb1 = *(const half8*)(bp + 8);
    u64 mm = mp[0];
    __syncthreads();

    f32x4 acc[4] = {};
    float mrow = -INFINITY, lp = 0.f;
    const int shg = 4 * g;

    int buf = 0;
    for (int kt = 0; kt < SS / 64; ++kt) {
        const bool more = (kt + 1 < SS / 64);
        const int jn = more ? (kt + 1) * 64 : 0;     // clamped (safe re-read)
        const int ktn = more ? kt + 1 : 0;

        // ---- issue next-tile loads (registers; hidden under compute)
        half8 k0n = *(const half8*)(Kbase + (size_t)(jn + srow0) * 64 + s * 8);
        half8 k1n = *(const half8*)(Kbase + (size_t)(jn + srow0 + 8) * 64 + s * 8);
        half8 v0n = *(const half8*)(Vbase + (size_t)srow0 * SS + jn + s * 8);
        half8 v1n = *(const half8*)(Vbase + (size_t)(srow0 + 8) * SS + jn + s * 8);
        half8 bbn0 = *(const half8*)(bp + jn);
        half8 bbn1 = *(const half8*)(bp + jn + 8);
        u64 mmn = mp[ktn];

        char* KsB = (char*)Ks[buf];
        char* VsB = (char*)Vs[buf];

        // ---- C-init: sc = mask ? bias : MASKNEG  (log2-domain)
        u64 sh = mm >> shg;
        f32x4 sc[4];
#pragma unroll
        for (int nt = 0; nt < 4; ++nt)
#pragma unroll
            for (int r = 0; r < 4; ++r) {
                float bf = (float)(nt < 2 ? bb0[nt * 4 + r] : bb1[(nt - 2) * 4 + r]);
                sc[nt][r] = ((sh >> (16 * nt + r)) & 1) ? bf : MASKNEG;
            }

        // ---- QK^T swapped: sc[nt][r] = S[key=nt*16+4g+r][q=c] + bias
        __builtin_amdgcn_s_setprio(1);
#pragma unroll
        for (int ks = 0; ks < 2; ++ks)
#pragma unroll
            for (int nt = 0; nt < 4; ++nt) {
                int row = nt * 16 + c;
                half8 kf = *(const half8*)(KsB + row * 128 +
                           ((ks * 64 + g * 16) ^ ((row & 7) << 4)));
                sc[nt] = __builtin_amdgcn_mfma_f32_16x16x32_f16(
                    kf, qf[ks], sc[nt], 0, 0, 0);
            }
        __builtin_amdgcn_s_setprio(0);

        // ---- lane-local softmax (base 2) with defer-max
        float rm = fmaxf(fmaxf(fmaxf(sc[0][0], sc[0][1]), fmaxf(sc[0][2], sc[0][3])),
                         fmaxf(fmaxf(sc[1][0], sc[1][1]), fmaxf(sc[1][2], sc[1][3])));
        rm = fmaxf(rm, fmaxf(fmaxf(fmaxf(sc[2][0], sc[2][1]), fmaxf(sc[2][2], sc[2][3])),
                             fmaxf(fmaxf(sc[3][0], sc[3][1]), fmaxf(sc[3][2], sc[3][3]))));
        rm = fmaxf(rm, __shfl_xor(rm, 16));
        rm = fmaxf(rm, __shfl_xor(rm, 32));
        if (!__all(rm <= mrow + 8.0f)) {
            float mn = fmaxf(mrow, rm);
            float scal = exp2f(mrow - mn);   // exp2(-inf)=0 first tile
            mrow = mn;
            lp *= scal;
            float sq[4];
#pragma unroll
            for (int r = 0; r < 4; ++r)
                sq[r] = __int_as_float(__builtin_amdgcn_ds_bpermute(
                            ga[r], __float_as_int(scal)));
#pragma unroll
            for (int nt = 0; nt < 4; ++nt)
#pragma unroll
                for (int r = 0; r < 4; ++r) acc[nt][r] *= sq[r];
        }
        float psum = 0.f;
#pragma unroll
        for (int nt = 0; nt < 4; ++nt)
#pragma unroll
            for (int r = 0; r < 4; ++r) {
                float p = exp2f(sc[nt][r] - mrow);
                sc[nt][r] = p;
                psum += p;
            }
        lp += psum;

        // ---- pack P in-register: pa[kk] = P[q=c][keys 16kk+4g+0..3]
        // scalar casts -> compiler emits v_cvt_pkrtz pairs (m240)
        half4 pa[4];
#pragma unroll
        for (int kk = 0; kk < 4; ++kk) {
            half4 pv = {(f16)sc[kk][0], (f16)sc[kk][1],
                        (f16)sc[kk][2], (f16)sc[kk][3]};
            pa[kk] = pv;
        }

        // ---- PV: acc[nt2][r] (+)= P @ V via 16x16x16, b128 V reads
        __builtin_amdgcn_s_setprio(1);
#pragma unroll
        for (int ks = 0; ks < 2; ++ks)
#pragma unroll
            for (int nt2 = 0; nt2 < 4; ++nt2) {
                int row = nt2 * 16 + c;
                half8 vf = *(const half8*)(VsB + row * 128 +
                           ((ks * 64 + g * 16) ^ ((row & 7) << 4)));
                half4 vlo = {vf[0], vf[1], vf[2], vf[3]};
                half4 vhi = {vf[4], vf[5], vf[6], vf[7]};
                acc[nt2] = __builtin_amdgcn_mfma_f32_16x16x16f16(
                    pa[2 * ks], vlo, acc[nt2], 0, 0, 0);
                acc[nt2] = __builtin_amdgcn_mfma_f32_16x16x16f16(
                    pa[2 * ks + 1], vhi, acc[nt2], 0, 0, 0);
            }
        __builtin_amdgcn_s_setprio(0);

        // ---- commit next tile: regs -> LDS buf^1 (vmcnt wait lands here)
        if (more) {
            char* kd = (char*)Ks[buf ^ 1];
            char* vd = (char*)Vs[buf ^ 1];
            *(half8*)(kd + srow0 * 128 + kdst) = k0n;
            *(half8*)(kd + (srow0 + 8) * 128 + kdst) = k1n;
            half4 lo0 = {v0n[0], v0n[1], v0n[2], v0n[3]}, hi0 = {v0n[4], v0n[5], v0n[6], v0n[7]};
            half4 lo1 = {v1n[0], v1n[1], v1n[2], v1n[3]}, hi1 = {v1n[4], v1n[5], v1n[6], v1n[7]};
            *(half4*)(vd + srow0 * 128 + vdlo) = lo0;
            *(half4*)(vd + srow0 * 128 + vdhi) = hi0;
            *(half4*)(vd + (srow0 + 8) * 128 + vdlo) = lo1;
            *(half4*)(vd + (srow0 + 8) * 128 + vdhi) = hi1;
            buf ^= 1;
            bb0 = bbn0; bb1 = bbn1; mm = mmn;
        }
        __syncthreads();   // one barrier per iteration
    }

    // ---- epilogue: cross-g sum of lp, gather per-row inverses, store
    float lt = lp;
    lt += __shfl_xor(lt, 16);
    lt += __shfl_xor(lt, 32);
    float linv[4];
#pragma unroll
    for (int r = 0; r < 4; ++r)
        linv[r] = 1.0f / __int_as_float(__builtin_amdgcn_ds_bpermute(
                      ga[r], __float_as_int(lt)));
#pragma unroll
    for (int r = 0; r < 4; ++r) {
        int qrow = q0 + wid * 16 + 4 * g + r;
#pragma unroll
        for (int nt2 = 0; nt2 < 4; ++nt2)
            AOh[((size_t)b * SS + qrow) * DD + h * 64 + nt2 * 16 + c] =
                (f16)(acc[nt2][r] * linv[r]);
    }
}

// ============================================================
// Output projection: out(f32) = AO(f16) @ Wo + bo.
// ============================================================
__global__ __launch_bounds__(256)
void gemm_out(const f16* __restrict__ A, const f16* __restrict__ BT,
              const float* __restrict__ bias, float* __restrict__ out)
{
    __shared__ f16 As[128 * 64];
    __shared__ f16 Bs[128 * 64];
    const int t = threadIdx.x, wid = t >> 6, l = t & 63, c = l & 15, g = l >> 4;
    const int m0 = blockIdx.y * 128, n0 = blockIdx.x * 128;
    const int wm = wid >> 1, wn = wid & 1;
    f32x4 acc[4][4] = {};
    char* AsB = (char*)As; char* BsB = (char*)Bs;

    for (int k0 = 0; k0 < DD; k0 += 64) {
        __syncthreads();
#pragma unroll
        for (int j = 0; j < 4; ++j) {
            int row = wid * 32 + j * 8 + (l >> 3);
            int slot = (l & 7) ^ (row & 7);
            gload16(A + (size_t)(m0 + row) * DD + k0 + slot * 8,
                    AsB + (wid * 32 + j * 8) * 128);
            gload16(BT + (size_t)(n0 + row) * DD + k0 + slot * 8,
                    BsB + (wid * 32 + j * 8) * 128);
        }
        __syncthreads();
#pragma unroll
        for (int ks = 0; ks < 2; ++ks) {
            half8 af[4];
#pragma unroll
            for (int mt = 0; mt < 4; ++mt) {
                int row = wm * 64 + mt * 16 + c;
                af[mt] = *(const half8*)(AsB + row * 128 +
                         ((ks * 64 + g * 16) ^ ((row & 7) << 4)));
            }
#pragma unroll
            for (int nt = 0; nt < 4; ++nt) {
                int row = wn * 64 + nt * 16 + c;
                half8 bf = *(const half8*)(BsB + row * 128 +
                           ((ks * 64 + g * 16) ^ ((row & 7) << 4)));
#pragma unroll
                for (int mt = 0; mt < 4; ++mt)
                    acc[mt][nt] = __builtin_amdgcn_mfma_f32_16x16x32_f16(
                        af[mt], bf, acc[mt][nt], 0, 0, 0);
            }
        }
    }
#pragma unroll
    for (int nt = 0; nt < 4; ++nt) {
        int n = n0 + wn * 64 + nt * 16 + c;
        float bn = bias[n];
#pragma unroll
        for (int mt = 0; mt < 4; ++mt)
#pragma unroll
            for (int reg = 0; reg < 4; ++reg) {
                int m = m0 + wm * 64 + mt * 16 + 4 * g + reg;
                out[(size_t)m * DD + n] = acc[mt][nt][reg] + bn;
            }
    }
}

extern "C" void kernel_launch(void* const* d_in, const int* in_sizes, int n_in,
                              void* d_out, int out_size, void* d_ws, size_t ws_size,
                              hipStream_t stream)
{
    (void)in_sizes; (void)n_in; (void)out_size; (void)ws_size;

    const float* query = (const float*)d_in[0];
    const float* key   = (const float*)d_in[1];
    const float* value = (const float*)d_in[2];
    const int*   mask  = (const int*)d_in[3];
    const float* rpb   = (const float*)d_in[4];
    const float* Wq = (const float*)d_in[5];  const float* bq = (const float*)d_in[6];
    const float* Wk = (const float*)d_in[7];  const float* bk = (const float*)d_in[8];
    const float* Wv = (const float*)d_in[9];  const float* bv = (const float*)d_in[10];
    const float* Wo = (const float*)d_in[11]; const float* bo = (const float*)d_in[12];
    float* out = (float*)d_out;

    // workspace layout (f16 elements). AOh aliases Xq (dead after proj3).
    const size_t NX = (size_t)2 * SS * DD;   // 4096x1024
    const size_t NW = (size_t)DD * DD;       // 1024x1024
    f16* Xq    = (f16*)d_ws;
    f16* Xk    = Xq + NX;
    f16* Xv    = Xk + NX;
    f16* WqT   = Xv + NX;
    f16* WkT   = WqT + NW;
    f16* WvT   = WkT + NW;
    f16* WoT   = WvT + NW;
    f16* Qw    = WoT + NW;
    f16* Kw    = Qw + NX;
    f16* VTw   = Kw + NX;
    f16* rpbT  = VTw + NX;                   // 16*2048*2048 f16 = 128 MB
    u64* mbits = (u64*)(rpbT + (size_t)HH * SS * SS);  // 1 MB
    f16* AOh   = Xq;   // alias

    cvt_x<<<dim3(NX / 2048, 1, 3), 256, 0, stream>>>(query, key, value, Xq, Xk, Xv);
    cvt_wT<<<dim3(16, 16, 4), 256, 0, stream>>>(Wq, Wk, Wv, Wo, WqT, WkT, WvT, WoT);
    cvt_rpbT3<<<dim3(SS / 16, SS / 64), 256, 0, stream>>>(rpb, rpbT);
    cvt_maskbits<<<dim3((2 * SS) / 4), 256, 0, stream>>>(mask, mbits);
    proj3<<<dim3(8, 32, 3), 256, 0, stream>>>(Xq, Xk, Xv, WqT, WkT, WvT,
                                              bq, bk, bv, Qw, Kw, VTw);
    attn_fwd<<<dim3(2 * HH, SS / 64), 256, 0, stream>>>(Qw, Kw, VTw, rpbT, mbits, AOh);
    gemm_out<<<dim3(8, 32), 256, 0, stream>>>(AOh, WoT, bo, out);
}